// Round 1
// baseline (10241.596 us; speedup 1.0000x reference)
//
#include <hip/hip_runtime.h>

#define BS 256

static __device__ __forceinline__ float relu_(float v) { return fmaxf(v, 0.0f); }

// ---- degree: deg[dst] += |attr| ----
__global__ void k_deg(const int* __restrict__ dst, const float* __restrict__ attr,
                      float* __restrict__ deg, int E) {
  int stride = gridDim.x * blockDim.x;
  for (int e = blockIdx.x * blockDim.x + threadIdx.x; e < E; e += stride)
    atomicAdd(&deg[dst[e]], fabsf(attr[e]));
}

// ---- dis = deg>0 ? 1/sqrt(deg) : 0  (in place) ----
__global__ void k_dis(float* __restrict__ deg, int N) {
  int n = blockIdx.x * blockDim.x + threadIdx.x;
  if (n < N) { float d = deg[n]; deg[n] = (d > 0.0f) ? (1.0f / sqrtf(d)) : 0.0f; }
}

// ---- scalar propagation: hout[dst] += norm(e) * hin[src] ----
__global__ void k_prop1(const int* __restrict__ src, const int* __restrict__ dst,
                        const float* __restrict__ attr, const float* __restrict__ dis,
                        const float* __restrict__ hin, float* __restrict__ hout, int E) {
  int stride = gridDim.x * blockDim.x;
  for (int e = blockIdx.x * blockDim.x + threadIdx.x; e < E; e += stride) {
    int s = src[e], d = dst[e];
    float w = fabsf(attr[e]) * dis[s] * dis[d];
    atomicAdd(&hout[d], w * hin[s]);
  }
}

// ---- 8-dim propagation: hout[dst][0..7] += norm(e) * hin[src][0..7] ----
__global__ void k_prop8(const int* __restrict__ src, const int* __restrict__ dst,
                        const float* __restrict__ attr, const float* __restrict__ dis,
                        const float* __restrict__ hin, float* __restrict__ hout, int E) {
  int stride = gridDim.x * blockDim.x;
  for (int e = blockIdx.x * blockDim.x + threadIdx.x; e < E; e += stride) {
    int s = src[e], d = dst[e];
    float w = fabsf(attr[e]) * dis[s] * dis[d];
    const float4* hp = (const float4*)(hin + (size_t)s * 8);
    float4 a = hp[0], b = hp[1];
    float* o = hout + (size_t)d * 8;
    atomicAdd(o + 0, w * a.x); atomicAdd(o + 1, w * a.y);
    atomicAdd(o + 2, w * a.z); atomicAdd(o + 3, w * a.w);
    atomicAdd(o + 4, w * b.x); atomicAdd(o + 5, w * b.y);
    atomicAdd(o + 6, w * b.z); atomicAdd(o + 7, w * b.w);
  }
}

// ---- layer1 epilogue: y[n][j] = relu(x*W1[0,j] + h1*W1[1,j] + h2*W1[2,j] + h3*W1[3,j] + b1[j]) ----
__global__ void k_layer1(const float* __restrict__ x, const float* __restrict__ h1,
                         const float* __restrict__ h2, const float* __restrict__ h3,
                         const float* __restrict__ W1, const float* __restrict__ b1,
                         float* __restrict__ y, int N) {
  int n = blockIdx.x * blockDim.x + threadIdx.x;
  if (n >= N) return;
  float xv = x[n], a = h1[n], b = h2[n], c = h3[n];
  float o[8];
#pragma unroll
  for (int j = 0; j < 8; ++j)
    o[j] = relu_(xv * W1[j] + a * W1[8 + j] + b * W1[16 + j] + c * W1[24 + j] + b1[j]);
  float4* op = (float4*)(y + (size_t)n * 8);
  op[0] = make_float4(o[0], o[1], o[2], o[3]);
  op[1] = make_float4(o[4], o[5], o[6], o[7]);
}

// ---- out[n][:] = y[n][:] @ W (8x8, W[i*8+j]) ----
__global__ void k_matvec8(const float* __restrict__ y, const float* __restrict__ W,
                          float* __restrict__ out, int N) {
  int n = blockIdx.x * blockDim.x + threadIdx.x;
  if (n >= N) return;
  const float4* yp = (const float4*)(y + (size_t)n * 8);
  float4 a = yp[0], b = yp[1];
  float yi[8] = {a.x, a.y, a.z, a.w, b.x, b.y, b.z, b.w};
  float o[8];
#pragma unroll
  for (int j = 0; j < 8; ++j) {
    float s = 0.0f;
#pragma unroll
    for (int i = 0; i < 8; ++i) s += yi[i] * W[i * 8 + j];
    o[j] = s;
  }
  float4* op = (float4*)(out + (size_t)n * 8);
  op[0] = make_float4(o[0], o[1], o[2], o[3]);
  op[1] = make_float4(o[4], o[5], o[6], o[7]);
}

// ---- layer2 epilogue + layer3 projections: z=relu(Q+b2); s_i[n] = z @ W3[i] ----
__global__ void k_layer3s(const float* __restrict__ Q, const float* __restrict__ b2,
                          const float* __restrict__ W3, float* __restrict__ S, int N) {
  int n = blockIdx.x * blockDim.x + threadIdx.x;
  if (n >= N) return;
  const float4* qp = (const float4*)(Q + (size_t)n * 8);
  float4 a = qp[0], b = qp[1];
  float z[8] = {a.x, a.y, a.z, a.w, b.x, b.y, b.z, b.w};
#pragma unroll
  for (int j = 0; j < 8; ++j) z[j] = relu_(z[j] + b2[j]);
#pragma unroll
  for (int i = 0; i < 4; ++i) {
    float s = 0.0f;
#pragma unroll
    for (int j = 0; j < 8; ++j) s += z[j] * W3[i * 8 + j];
    S[(size_t)i * N + n] = s;
  }
}

// ---- r = relu(v3 + b3); acc[0] += sum(r)  (double accumulation) ----
__global__ void k_relusum(const float* __restrict__ v3, const float* __restrict__ b3,
                          float* __restrict__ r, double* __restrict__ acc, int N) {
  int n = blockIdx.x * blockDim.x + threadIdx.x;
  double v = 0.0;
  if (n < N) { float rv = relu_(v3[n] + b3[0]); r[n] = rv; v = (double)rv; }
#pragma unroll
  for (int off = 32; off; off >>= 1) v += __shfl_down(v, off);
  if ((threadIdx.x & 63) == 0) atomicAdd(acc, v);
}

__global__ void k_mean(const double* __restrict__ acc, float* __restrict__ stats, int N) {
  stats[0] = (float)(acc[0] / (double)N);
}

__global__ void k_var(const float* __restrict__ r, const float* __restrict__ stats,
                      double* __restrict__ acc, int N) {
  int n = blockIdx.x * blockDim.x + threadIdx.x;
  double v = 0.0;
  if (n < N) { float d = r[n] - stats[0]; v = (double)d * (double)d; }
#pragma unroll
  for (int off = 32; off; off >>= 1) v += __shfl_down(v, off);
  if ((threadIdx.x & 63) == 0) atomicAdd(acc + 1, v);
}

__global__ void k_finstats(const double* __restrict__ acc, float* __restrict__ stats, int N) {
  double var = acc[1] / (double)N;
  stats[1] = (float)(1.0 / sqrt(var + 1e-5));
}

// ---- normalize, emit x column, build sortable keys ----
__global__ void k_normalize(const float* __restrict__ r, const float* __restrict__ stats,
                            float* __restrict__ out, unsigned* __restrict__ keys, int N) {
  int n = blockIdx.x * blockDim.x + threadIdx.x;
  if (n >= N) return;
  float xv = (r[n] - stats[0]) * stats[1];
  out[2 * (size_t)n] = xv;
  unsigned u = __float_as_uint(xv);
  u = (u & 0x80000000u) ? ~u : (u | 0x80000000u);
  keys[n] = u;
}

__global__ void k_stateinit(unsigned* __restrict__ state, const int* __restrict__ kp) {
  state[0] = 0u;                 // prefix
  state[1] = (unsigned)kp[0];    // remaining
}

// ---- radix-select histogram pass ----
__global__ void k_hist(const unsigned* __restrict__ keys, int N,
                       const unsigned* __restrict__ state, unsigned* __restrict__ hist,
                       int shift) {
  __shared__ unsigned sh[256];
  sh[threadIdx.x] = 0;
  __syncthreads();
  unsigned prefix = state[0];
  unsigned hmask = (shift >= 24) ? 0u : (0xFFFFFFFFu << (shift + 8));
  int stride = gridDim.x * blockDim.x;
  for (int n = blockIdx.x * blockDim.x + threadIdx.x; n < N; n += stride) {
    unsigned kk = keys[n];
    if ((kk & hmask) == (prefix & hmask)) atomicAdd(&sh[(kk >> shift) & 255u], 1u);
  }
  __syncthreads();
  atomicAdd(&hist[threadIdx.x], sh[threadIdx.x]);
}

__global__ void k_select(unsigned* __restrict__ state, unsigned* __restrict__ hist, int shift) {
  unsigned rem = state[1];
  unsigned cum = 0;
  int b = 255;
  for (; b >= 0; --b) {
    unsigned c = hist[b];
    if (cum + c >= rem) break;
    cum += c;
  }
  if (b < 0) b = 0;
  state[0] |= ((unsigned)b) << shift;
  state[1] = rem - cum;
  for (int i = 0; i < 256; ++i) hist[i] = 0;
}

// ---- mark > T; count ==T per 256-block ----
__global__ void k_mark(const unsigned* __restrict__ keys, int N,
                       const unsigned* __restrict__ state, float* __restrict__ out,
                       unsigned* __restrict__ blkcnt) {
  unsigned T = state[0];
  int n = blockIdx.x * 256 + threadIdx.x;
  int eq = 0;
  __shared__ int sh;
  if (threadIdx.x == 0) sh = 0;
  __syncthreads();
  if (n < N) {
    unsigned kk = keys[n];
    out[2 * (size_t)n + 1] = (kk > T) ? 1.0f : 0.0f;
    eq = (kk == T);
  }
  if (eq) atomicAdd(&sh, 1);
  __syncthreads();
  if (threadIdx.x == 0) blkcnt[blockIdx.x] = (unsigned)sh;
}

__global__ void k_scan(const unsigned* __restrict__ blkcnt, unsigned* __restrict__ scanbuf, int NB) {
  unsigned a = 0;
  for (int i = 0; i < NB; ++i) { scanbuf[i] = a; a += blkcnt[i]; }
}

// ---- resolve ties: lowest index first, rank < m gets 1 ----
__global__ void k_resolve(const unsigned* __restrict__ keys, int N,
                          const unsigned* __restrict__ state,
                          const unsigned* __restrict__ scanbuf, float* __restrict__ out) {
  unsigned T = state[0];
  unsigned m = state[1];
  int n = blockIdx.x * 256 + threadIdx.x;
  if (n >= N) return;
  if (keys[n] != T) return;
  unsigned rank = scanbuf[blockIdx.x];
  int base = blockIdx.x * 256;
  for (int j = base; j < n; ++j) rank += (keys[j] == T);
  out[2 * (size_t)n + 1] = (rank < m) ? 1.0f : 0.0f;
}

extern "C" void kernel_launch(void* const* d_in, const int* in_sizes, int n_in,
                              void* d_out, int out_size, void* d_ws, size_t ws_size,
                              hipStream_t stream) {
  const float* x    = (const float*)d_in[0];
  const int*   ei   = (const int*)d_in[1];
  const float* attr = (const float*)d_in[2];
  const int*   kp   = (const int*)d_in[3];
  const float* W1   = (const float*)d_in[4];
  const float* b1   = (const float*)d_in[5];
  const float* W2   = (const float*)d_in[6];
  const float* b2   = (const float*)d_in[7];
  const float* W3   = (const float*)d_in[8];
  const float* b3   = (const float*)d_in[9];
  const int N = in_sizes[0];
  const int E = in_sizes[2];
  const int* src = ei;
  const int* dst = ei + E;

  float* fws = (float*)d_ws;
  float* dis = fws;
  float* h1  = fws + (size_t)N;
  float* h2  = fws + (size_t)2 * N;
  float* h3  = fws + (size_t)3 * N;
  float* y   = fws + (size_t)4 * N;
  float* P   = fws + (size_t)12 * N;
  float* Q   = fws + (size_t)20 * N;
  float* S   = fws + (size_t)28 * N;   // s0..s3 at S + i*N
  float* r   = fws + (size_t)32 * N;
  unsigned* keys = (unsigned*)(fws + (size_t)33 * N);
  char* small_ = (char*)(fws + (size_t)34 * N);
  double*   acc    = (double*)small_;               // 2 doubles
  float*    stats  = (float*)(small_ + 16);         // mean, inv_std
  unsigned* state  = (unsigned*)(small_ + 24);      // prefix, remaining
  unsigned* hist   = (unsigned*)(small_ + 32);      // 256
  const int NB = (N + 255) / 256;
  unsigned* blkcnt  = (unsigned*)(small_ + 32 + 1024);
  unsigned* scanbuf = blkcnt + NB;

  hipMemsetAsync(fws, 0, (size_t)4 * N * sizeof(float), stream);   // deg,h1,h2,h3
  hipMemsetAsync(small_, 0, 32 + 1024, stream);                    // acc,stats,state,hist

  int ge = (E + BS - 1) / BS; if (ge > 4096) ge = 4096;
  dim3 GE(ge), GN(NB), B(BS);

  k_deg<<<GE, B, 0, stream>>>(dst, attr, dis, E);
  k_dis<<<GN, B, 0, stream>>>(dis, N);

  // layer 1: three scalar propagations
  k_prop1<<<GE, B, 0, stream>>>(src, dst, attr, dis, x,  h1, E);
  k_prop1<<<GE, B, 0, stream>>>(src, dst, attr, dis, h1, h2, E);
  k_prop1<<<GE, B, 0, stream>>>(src, dst, attr, dis, h2, h3, E);
  k_layer1<<<GN, B, 0, stream>>>(x, h1, h2, h3, W1, b1, y, N);

  // layer 2: Horner, three 8-dim propagations
  k_matvec8<<<GN, B, 0, stream>>>(y, W2 + 3 * 64, P, N);
  k_matvec8<<<GN, B, 0, stream>>>(y, W2 + 2 * 64, Q, N);
  k_prop8<<<GE, B, 0, stream>>>(src, dst, attr, dis, P, Q, E);
  k_matvec8<<<GN, B, 0, stream>>>(y, W2 + 1 * 64, P, N);
  k_prop8<<<GE, B, 0, stream>>>(src, dst, attr, dis, Q, P, E);
  k_matvec8<<<GN, B, 0, stream>>>(y, W2 + 0 * 64, Q, N);
  k_prop8<<<GE, B, 0, stream>>>(src, dst, attr, dis, P, Q, E);

  // layer 3: project to 4 scalars, Horner with scalar propagations
  k_layer3s<<<GN, B, 0, stream>>>(Q, b2, W3, S, N);
  k_prop1<<<GE, B, 0, stream>>>(src, dst, attr, dis, S + 3 * (size_t)N, S + 2 * (size_t)N, E);
  k_prop1<<<GE, B, 0, stream>>>(src, dst, attr, dis, S + 2 * (size_t)N, S + 1 * (size_t)N, E);
  k_prop1<<<GE, B, 0, stream>>>(src, dst, attr, dis, S + 1 * (size_t)N, S + 0 * (size_t)N, E);

  // layernorm stats (two-pass, double accum)
  k_relusum<<<GN, B, 0, stream>>>(S, b3, r, acc, N);
  k_mean<<<1, 1, 0, stream>>>(acc, stats, N);
  k_var<<<GN, B, 0, stream>>>(r, stats, acc, N);
  k_finstats<<<1, 1, 0, stream>>>(acc, stats, N);

  float* out = (float*)d_out;
  k_normalize<<<GN, B, 0, stream>>>(r, stats, out, keys, N);

  // exact device-side radix top-k selection
  k_stateinit<<<1, 1, 0, stream>>>(state, kp);
  for (int shift = 24; shift >= 0; shift -= 8) {
    k_hist<<<GN, B, 0, stream>>>(keys, N, state, hist, shift);
    k_select<<<1, 1, 0, stream>>>(state, hist, shift);
  }
  k_mark<<<GN, B, 0, stream>>>(keys, N, state, out, blkcnt);
  k_scan<<<1, 1, 0, stream>>>(blkcnt, scanbuf, NB);
  k_resolve<<<GN, B, 0, stream>>>(keys, N, state, scanbuf, out);
}

// Round 2
// 1293.875 us; speedup vs baseline: 7.9154x; 7.9154x over previous
//
#include <hip/hip_runtime.h>

#define BS 256
#define GPN 16   // lanes cooperating per node

static __device__ __forceinline__ float relu_(float v) { return fmaxf(v, 0.0f); }

// ======================= CSR build =======================

__global__ void k_count(const int* __restrict__ dst, int* __restrict__ cnt, int E) {
  int e = blockIdx.x * blockDim.x + threadIdx.x;
  if (e < E) atomicAdd(&cnt[dst[e]], 1);
}

// block sums of 1024-element chunks
__global__ void k_scanA(const int* __restrict__ cnt, int* __restrict__ bsum, int N) {
  __shared__ int sh[BS];
  int t = threadIdx.x;
  int base = blockIdx.x * 1024;
  int s = 0;
#pragma unroll
  for (int j = 0; j < 4; ++j) { int i = base + t * 4 + j; s += (i < N) ? cnt[i] : 0; }
  sh[t] = s; __syncthreads();
  for (int off = 128; off; off >>= 1) { if (t < off) sh[t] += sh[t + off]; __syncthreads(); }
  if (t == 0) bsum[blockIdx.x] = sh[0];
}

// exclusive scan of block sums (NB2 <= 256)
__global__ void k_scanB(int* __restrict__ bsum, int NB2) {
  __shared__ int sh[BS];
  int t = threadIdx.x;
  int v = (t < NB2) ? bsum[t] : 0;
  sh[t] = v; __syncthreads();
  for (int off = 1; off < BS; off <<= 1) {
    int add = (t >= off) ? sh[t - off] : 0; __syncthreads();
    sh[t] += add; __syncthreads();
  }
  if (t < NB2) bsum[t] = sh[t] - v;
}

// write rowptr (exclusive) + cursor copy
__global__ void k_scanC(const int* __restrict__ cnt, const int* __restrict__ bsum,
                        int* __restrict__ rowptr, int* __restrict__ cursor, int N, int E) {
  __shared__ int sh[BS];
  int b = blockIdx.x, t = threadIdx.x;
  int base = b * 1024;
  int c[4]; int s = 0;
#pragma unroll
  for (int j = 0; j < 4; ++j) { int i = base + t * 4 + j; c[j] = (i < N) ? cnt[i] : 0; s += c[j]; }
  sh[t] = s; __syncthreads();
  for (int off = 1; off < BS; off <<= 1) {
    int add = (t >= off) ? sh[t - off] : 0; __syncthreads();
    sh[t] += add; __syncthreads();
  }
  int run = sh[t] - s + bsum[b];
#pragma unroll
  for (int j = 0; j < 4; ++j) {
    int i = base + t * 4 + j;
    if (i < N) { rowptr[i] = run; cursor[i] = run; run += c[j]; }
  }
  if (b == 0 && t == 0) rowptr[N] = E;
}

// scatter edges into CSR slots: adj[pos] = {src, |attr|}
__global__ void k_place(const int* __restrict__ src, const int* __restrict__ dst,
                        const float* __restrict__ attr, int* __restrict__ cursor,
                        int2* __restrict__ adj, int E) {
  int e = blockIdx.x * blockDim.x + threadIdx.x;
  if (e >= E) return;
  int d = dst[e];
  int pos = atomicAdd(&cursor[d], 1);
  adj[pos] = make_int2(src[e], __float_as_int(fabsf(attr[e])));
}

// deg[n] = sum |attr| over incoming; dis = deg>0 ? 1/sqrt(deg) : 0
__global__ void k_degdis(const int* __restrict__ rowptr, const int2* __restrict__ adj,
                         float* __restrict__ dis, int N) {
  int g = (blockIdx.x * blockDim.x + threadIdx.x) / GPN;
  int l = threadIdx.x & (GPN - 1);
  if (g >= N) return;
  int beg = rowptr[g], end = rowptr[g + 1];
  float s = 0.0f;
  for (int e = beg + l; e < end; e += GPN) s += __int_as_float(adj[e].y);
#pragma unroll
  for (int off = 8; off; off >>= 1) s += __shfl_xor(s, off, GPN);
  if (l == 0) dis[g] = (s > 0.0f) ? (1.0f / sqrtf(s)) : 0.0f;
}

// w *= dis[src] * dis[n]
__global__ void k_scalecsr(const int* __restrict__ rowptr, int2* adj,
                           const float* __restrict__ dis, int N) {
  int g = (blockIdx.x * blockDim.x + threadIdx.x) / GPN;
  int l = threadIdx.x & (GPN - 1);
  if (g >= N) return;
  float dn = dis[g];
  int beg = rowptr[g], end = rowptr[g + 1];
  for (int e = beg + l; e < end; e += GPN) {
    int2 sw = adj[e];
    float w = __int_as_float(sw.y) * dis[sw.x] * dn;
    adj[e] = make_int2(sw.x, __float_as_int(w));
  }
}

// ======================= gather props =======================

// hout[n] = (base?base[n]:0) + sum_e w*hin[src]
__global__ void k_gprop1(const int* __restrict__ rowptr, const int2* __restrict__ adj,
                         const float* __restrict__ hin, const float* __restrict__ base,
                         float* __restrict__ hout, int N) {
  int g = (blockIdx.x * blockDim.x + threadIdx.x) / GPN;
  int l = threadIdx.x & (GPN - 1);
  if (g >= N) return;
  int beg = rowptr[g], end = rowptr[g + 1];
  float acc = 0.0f;
  for (int e = beg + l; e < end; e += GPN) {
    int2 sw = adj[e];
    acc += __int_as_float(sw.y) * hin[sw.x];
  }
#pragma unroll
  for (int off = 8; off; off >>= 1) acc += __shfl_xor(acc, off, GPN);
  if (l == 0) hout[g] = (base ? base[g] : 0.0f) + acc;
}

// third layer-1 prop fused with y-epilogue:
// h3 = A h2 (computed here); y = relu(x W1[0] + h1 W1[1] + h2 W1[2] + h3 W1[3] + b1)
__global__ void k_gprop1_y(const int* __restrict__ rowptr, const int2* __restrict__ adj,
                           const float* __restrict__ h2, const float* __restrict__ x,
                           const float* __restrict__ h1, const float* __restrict__ W1,
                           const float* __restrict__ b1, float* __restrict__ y, int N) {
  int g = (blockIdx.x * blockDim.x + threadIdx.x) / GPN;
  int l = threadIdx.x & (GPN - 1);
  if (g >= N) return;
  int beg = rowptr[g], end = rowptr[g + 1];
  float acc = 0.0f;
  for (int e = beg + l; e < end; e += GPN) {
    int2 sw = adj[e];
    acc += __int_as_float(sw.y) * h2[sw.x];
  }
#pragma unroll
  for (int off = 8; off; off >>= 1) acc += __shfl_xor(acc, off, GPN);
  if (l == 0) {
    float xv = x[g], a = h1[g], b = h2[g], c = acc;
    float o[8];
#pragma unroll
    for (int j = 0; j < 8; ++j)
      o[j] = relu_(xv * W1[j] + a * W1[8 + j] + b * W1[16 + j] + c * W1[24 + j] + b1[j]);
    float4* op = (float4*)(y + (size_t)g * 8);
    op[0] = make_float4(o[0], o[1], o[2], o[3]);
    op[1] = make_float4(o[4], o[5], o[6], o[7]);
  }
}

// 8-dim gather prop with fused Horner base: hout[n][:] = y[n]@W + sum_e w*hin[src][:]
__global__ void k_gprop8(const int* __restrict__ rowptr, const int2* __restrict__ adj,
                         const float* __restrict__ hin, const float* __restrict__ y,
                         const float* __restrict__ W, float* __restrict__ hout, int N) {
  int g = (blockIdx.x * blockDim.x + threadIdx.x) / GPN;
  int l = threadIdx.x & (GPN - 1);
  if (g >= N) return;
  int beg = rowptr[g], end = rowptr[g + 1];
  float a0=0,a1=0,a2=0,a3=0,a4=0,a5=0,a6=0,a7=0;
  for (int e = beg + l; e < end; e += GPN) {
    int2 sw = adj[e];
    float w = __int_as_float(sw.y);
    const float4* hp = (const float4*)(hin + (size_t)sw.x * 8);
    float4 u = hp[0], v = hp[1];
    a0 += w*u.x; a1 += w*u.y; a2 += w*u.z; a3 += w*u.w;
    a4 += w*v.x; a5 += w*v.y; a6 += w*v.z; a7 += w*v.w;
  }
#pragma unroll
  for (int off = 8; off; off >>= 1) {
    a0 += __shfl_xor(a0, off, GPN); a1 += __shfl_xor(a1, off, GPN);
    a2 += __shfl_xor(a2, off, GPN); a3 += __shfl_xor(a3, off, GPN);
    a4 += __shfl_xor(a4, off, GPN); a5 += __shfl_xor(a5, off, GPN);
    a6 += __shfl_xor(a6, off, GPN); a7 += __shfl_xor(a7, off, GPN);
  }
  if (l == 0) {
    const float4* yp = (const float4*)(y + (size_t)g * 8);
    float4 u = yp[0], v = yp[1];
    float yi[8] = {u.x, u.y, u.z, u.w, v.x, v.y, v.z, v.w};
    float acc[8] = {a0, a1, a2, a3, a4, a5, a6, a7};
    float o[8];
#pragma unroll
    for (int j = 0; j < 8; ++j) {
      float s = acc[j];
#pragma unroll
      for (int i = 0; i < 8; ++i) s += yi[i] * W[i * 8 + j];
      o[j] = s;
    }
    float4* op = (float4*)(hout + (size_t)g * 8);
    op[0] = make_float4(o[0], o[1], o[2], o[3]);
    op[1] = make_float4(o[4], o[5], o[6], o[7]);
  }
}

// final layer-2 prop fused with relu(+b2) and the 4 layer-3 projections
__global__ void k_gprop8_fin(const int* __restrict__ rowptr, const int2* __restrict__ adj,
                             const float* __restrict__ hin, const float* __restrict__ y,
                             const float* __restrict__ W0, const float* __restrict__ b2,
                             const float* __restrict__ W3, float* __restrict__ S, int N) {
  int g = (blockIdx.x * blockDim.x + threadIdx.x) / GPN;
  int l = threadIdx.x & (GPN - 1);
  if (g >= N) return;
  int beg = rowptr[g], end = rowptr[g + 1];
  float a0=0,a1=0,a2=0,a3=0,a4=0,a5=0,a6=0,a7=0;
  for (int e = beg + l; e < end; e += GPN) {
    int2 sw = adj[e];
    float w = __int_as_float(sw.y);
    const float4* hp = (const float4*)(hin + (size_t)sw.x * 8);
    float4 u = hp[0], v = hp[1];
    a0 += w*u.x; a1 += w*u.y; a2 += w*u.z; a3 += w*u.w;
    a4 += w*v.x; a5 += w*v.y; a6 += w*v.z; a7 += w*v.w;
  }
#pragma unroll
  for (int off = 8; off; off >>= 1) {
    a0 += __shfl_xor(a0, off, GPN); a1 += __shfl_xor(a1, off, GPN);
    a2 += __shfl_xor(a2, off, GPN); a3 += __shfl_xor(a3, off, GPN);
    a4 += __shfl_xor(a4, off, GPN); a5 += __shfl_xor(a5, off, GPN);
    a6 += __shfl_xor(a6, off, GPN); a7 += __shfl_xor(a7, off, GPN);
  }
  if (l == 0) {
    const float4* yp = (const float4*)(y + (size_t)g * 8);
    float4 u = yp[0], v = yp[1];
    float yi[8] = {u.x, u.y, u.z, u.w, v.x, v.y, v.z, v.w};
    float acc[8] = {a0, a1, a2, a3, a4, a5, a6, a7};
    float z[8];
#pragma unroll
    for (int j = 0; j < 8; ++j) {
      float s = acc[j];
#pragma unroll
      for (int i = 0; i < 8; ++i) s += yi[i] * W0[i * 8 + j];
      z[j] = relu_(s + b2[j]);
    }
#pragma unroll
    for (int i = 0; i < 4; ++i) {
      float s = 0.0f;
#pragma unroll
      for (int j = 0; j < 8; ++j) s += z[j] * W3[i * 8 + j];
      S[(size_t)i * N + g] = s;
    }
  }
}

// ======================= shared node kernels =======================

__global__ void k_matvec8(const float* __restrict__ y, const float* __restrict__ W,
                          float* __restrict__ out, int N) {
  int n = blockIdx.x * blockDim.x + threadIdx.x;
  if (n >= N) return;
  const float4* yp = (const float4*)(y + (size_t)n * 8);
  float4 a = yp[0], b = yp[1];
  float yi[8] = {a.x, a.y, a.z, a.w, b.x, b.y, b.z, b.w};
  float o[8];
#pragma unroll
  for (int j = 0; j < 8; ++j) {
    float s = 0.0f;
#pragma unroll
    for (int i = 0; i < 8; ++i) s += yi[i] * W[i * 8 + j];
    o[j] = s;
  }
  float4* op = (float4*)(out + (size_t)n * 8);
  op[0] = make_float4(o[0], o[1], o[2], o[3]);
  op[1] = make_float4(o[4], o[5], o[6], o[7]);
}

__global__ void k_relusum(const float* __restrict__ v3, const float* __restrict__ b3,
                          float* __restrict__ r, double* __restrict__ acc, int N) {
  int n = blockIdx.x * blockDim.x + threadIdx.x;
  double v = 0.0;
  if (n < N) { float rv = relu_(v3[n] + b3[0]); r[n] = rv; v = (double)rv; }
#pragma unroll
  for (int off = 32; off; off >>= 1) v += __shfl_down(v, off);
  if ((threadIdx.x & 63) == 0) atomicAdd(acc, v);
}

__global__ void k_mean(const double* __restrict__ acc, float* __restrict__ stats, int N) {
  stats[0] = (float)(acc[0] / (double)N);
}

__global__ void k_var(const float* __restrict__ r, const float* __restrict__ stats,
                      double* __restrict__ acc, int N) {
  int n = blockIdx.x * blockDim.x + threadIdx.x;
  double v = 0.0;
  if (n < N) { float d = r[n] - stats[0]; v = (double)d * (double)d; }
#pragma unroll
  for (int off = 32; off; off >>= 1) v += __shfl_down(v, off);
  if ((threadIdx.x & 63) == 0) atomicAdd(acc + 1, v);
}

__global__ void k_finstats(const double* __restrict__ acc, float* __restrict__ stats, int N) {
  double var = acc[1] / (double)N;
  stats[1] = (float)(1.0 / sqrt(var + 1e-5));
}

__global__ void k_normalize(const float* __restrict__ r, const float* __restrict__ stats,
                            float* __restrict__ out, unsigned* __restrict__ keys, int N) {
  int n = blockIdx.x * blockDim.x + threadIdx.x;
  if (n >= N) return;
  float xv = (r[n] - stats[0]) * stats[1];
  out[2 * (size_t)n] = xv;
  unsigned u = __float_as_uint(xv);
  u = (u & 0x80000000u) ? ~u : (u | 0x80000000u);
  keys[n] = u;
}

__global__ void k_stateinit(unsigned* __restrict__ state, const int* __restrict__ kp) {
  state[0] = 0u;
  state[1] = (unsigned)kp[0];
}

__global__ void k_hist(const unsigned* __restrict__ keys, int N,
                       const unsigned* __restrict__ state, unsigned* __restrict__ hist,
                       int shift) {
  __shared__ unsigned sh[256];
  sh[threadIdx.x] = 0;
  __syncthreads();
  unsigned prefix = state[0];
  unsigned hmask = (shift >= 24) ? 0u : (0xFFFFFFFFu << (shift + 8));
  int stride = gridDim.x * blockDim.x;
  for (int n = blockIdx.x * blockDim.x + threadIdx.x; n < N; n += stride) {
    unsigned kk = keys[n];
    if ((kk & hmask) == (prefix & hmask)) atomicAdd(&sh[(kk >> shift) & 255u], 1u);
  }
  __syncthreads();
  atomicAdd(&hist[threadIdx.x], sh[threadIdx.x]);
}

__global__ void k_select(unsigned* __restrict__ state, unsigned* __restrict__ hist, int shift) {
  unsigned rem = state[1];
  unsigned cum = 0;
  int b = 255;
  for (; b >= 0; --b) {
    unsigned c = hist[b];
    if (cum + c >= rem) break;
    cum += c;
  }
  if (b < 0) b = 0;
  state[0] |= ((unsigned)b) << shift;
  state[1] = rem - cum;
  for (int i = 0; i < 256; ++i) hist[i] = 0;
}

__global__ void k_mark(const unsigned* __restrict__ keys, int N,
                       const unsigned* __restrict__ state, float* __restrict__ out,
                       unsigned* __restrict__ blkcnt) {
  unsigned T = state[0];
  int n = blockIdx.x * 256 + threadIdx.x;
  int eq = 0;
  __shared__ int sh;
  if (threadIdx.x == 0) sh = 0;
  __syncthreads();
  if (n < N) {
    unsigned kk = keys[n];
    out[2 * (size_t)n + 1] = (kk > T) ? 1.0f : 0.0f;
    eq = (kk == T);
  }
  if (eq) atomicAdd(&sh, 1);
  __syncthreads();
  if (threadIdx.x == 0) blkcnt[blockIdx.x] = (unsigned)sh;
}

// parallel exclusive scan of blkcnt (NB <= 512)
__global__ void k_scanP(const unsigned* __restrict__ blkcnt, unsigned* __restrict__ scanbuf, int NB) {
  __shared__ unsigned sh[BS];
  int t = threadIdx.x;
  unsigned c0 = (2 * t < NB) ? blkcnt[2 * t] : 0u;
  unsigned c1 = (2 * t + 1 < NB) ? blkcnt[2 * t + 1] : 0u;
  unsigned s = c0 + c1;
  sh[t] = s; __syncthreads();
  for (int off = 1; off < BS; off <<= 1) {
    unsigned add = (t >= off) ? sh[t - off] : 0u; __syncthreads();
    sh[t] += add; __syncthreads();
  }
  unsigned ex = sh[t] - s;
  if (2 * t < NB) scanbuf[2 * t] = ex;
  if (2 * t + 1 < NB) scanbuf[2 * t + 1] = ex + c0;
}

__global__ void k_resolve(const unsigned* __restrict__ keys, int N,
                          const unsigned* __restrict__ state,
                          const unsigned* __restrict__ scanbuf, float* __restrict__ out) {
  unsigned T = state[0];
  unsigned m = state[1];
  int n = blockIdx.x * 256 + threadIdx.x;
  if (n >= N) return;
  if (keys[n] != T) return;
  unsigned rank = scanbuf[blockIdx.x];
  int base = blockIdx.x * 256;
  for (int j = base; j < n; ++j) rank += (keys[j] == T);
  out[2 * (size_t)n + 1] = (rank < m) ? 1.0f : 0.0f;
}

// ======================= fallback (round-1) scatter kernels =======================

__global__ void k_deg(const int* __restrict__ dst, const float* __restrict__ attr,
                      float* __restrict__ deg, int E) {
  int stride = gridDim.x * blockDim.x;
  for (int e = blockIdx.x * blockDim.x + threadIdx.x; e < E; e += stride)
    atomicAdd(&deg[dst[e]], fabsf(attr[e]));
}

__global__ void k_dis(float* __restrict__ deg, int N) {
  int n = blockIdx.x * blockDim.x + threadIdx.x;
  if (n < N) { float d = deg[n]; deg[n] = (d > 0.0f) ? (1.0f / sqrtf(d)) : 0.0f; }
}

__global__ void k_prop1(const int* __restrict__ src, const int* __restrict__ dst,
                        const float* __restrict__ attr, const float* __restrict__ dis,
                        const float* __restrict__ hin, float* __restrict__ hout, int E) {
  int stride = gridDim.x * blockDim.x;
  for (int e = blockIdx.x * blockDim.x + threadIdx.x; e < E; e += stride) {
    int s = src[e], d = dst[e];
    float w = fabsf(attr[e]) * dis[s] * dis[d];
    atomicAdd(&hout[d], w * hin[s]);
  }
}

__global__ void k_prop8(const int* __restrict__ src, const int* __restrict__ dst,
                        const float* __restrict__ attr, const float* __restrict__ dis,
                        const float* __restrict__ hin, float* __restrict__ hout, int E) {
  int stride = gridDim.x * blockDim.x;
  for (int e = blockIdx.x * blockDim.x + threadIdx.x; e < E; e += stride) {
    int s = src[e], d = dst[e];
    float w = fabsf(attr[e]) * dis[s] * dis[d];
    const float4* hp = (const float4*)(hin + (size_t)s * 8);
    float4 a = hp[0], b = hp[1];
    float* o = hout + (size_t)d * 8;
    atomicAdd(o + 0, w * a.x); atomicAdd(o + 1, w * a.y);
    atomicAdd(o + 2, w * a.z); atomicAdd(o + 3, w * a.w);
    atomicAdd(o + 4, w * b.x); atomicAdd(o + 5, w * b.y);
    atomicAdd(o + 6, w * b.z); atomicAdd(o + 7, w * b.w);
  }
}

__global__ void k_layer1(const float* __restrict__ x, const float* __restrict__ h1,
                         const float* __restrict__ h2, const float* __restrict__ h3,
                         const float* __restrict__ W1, const float* __restrict__ b1,
                         float* __restrict__ y, int N) {
  int n = blockIdx.x * blockDim.x + threadIdx.x;
  if (n >= N) return;
  float xv = x[n], a = h1[n], b = h2[n], c = h3[n];
  float o[8];
#pragma unroll
  for (int j = 0; j < 8; ++j)
    o[j] = relu_(xv * W1[j] + a * W1[8 + j] + b * W1[16 + j] + c * W1[24 + j] + b1[j]);
  float4* op = (float4*)(y + (size_t)n * 8);
  op[0] = make_float4(o[0], o[1], o[2], o[3]);
  op[1] = make_float4(o[4], o[5], o[6], o[7]);
}

__global__ void k_layer3s(const float* __restrict__ Q, const float* __restrict__ b2,
                          const float* __restrict__ W3, float* __restrict__ S, int N) {
  int n = blockIdx.x * blockDim.x + threadIdx.x;
  if (n >= N) return;
  const float4* qp = (const float4*)(Q + (size_t)n * 8);
  float4 a = qp[0], b = qp[1];
  float z[8] = {a.x, a.y, a.z, a.w, b.x, b.y, b.z, b.w};
#pragma unroll
  for (int j = 0; j < 8; ++j) z[j] = relu_(z[j] + b2[j]);
#pragma unroll
  for (int i = 0; i < 4; ++i) {
    float s = 0.0f;
#pragma unroll
    for (int j = 0; j < 8; ++j) s += z[j] * W3[i * 8 + j];
    S[(size_t)i * N + n] = s;
  }
}

// ======================= launcher =======================

extern "C" void kernel_launch(void* const* d_in, const int* in_sizes, int n_in,
                              void* d_out, int out_size, void* d_ws, size_t ws_size,
                              hipStream_t stream) {
  const float* x    = (const float*)d_in[0];
  const int*   ei   = (const int*)d_in[1];
  const float* attr = (const float*)d_in[2];
  const int*   kp   = (const int*)d_in[3];
  const float* W1   = (const float*)d_in[4];
  const float* b1   = (const float*)d_in[5];
  const float* W2   = (const float*)d_in[6];
  const float* b2   = (const float*)d_in[7];
  const float* W3   = (const float*)d_in[8];
  const float* b3   = (const float*)d_in[9];
  const int N = in_sizes[0];
  const int E = in_sizes[2];
  const int* src = ei;
  const int* dst = ei + E;
  float* out = (float*)d_out;
  const int NB  = (N + 255) / 256;
  const int NB2 = (N + 1023) / 1024;

  // ---- bump allocator over d_ws ----
  char* p = (char*)d_ws;
  auto alloc = [&](size_t bytes) -> char* {
    char* r = p; p += (bytes + 255) & ~(size_t)255; return r;
  };
  float*    dis    = (float*)alloc((size_t)N * 4);
  float*    h1     = (float*)alloc((size_t)N * 4);
  float*    h2     = (float*)alloc((size_t)N * 4);
  float*    y      = (float*)alloc((size_t)N * 32);
  float*    P      = (float*)alloc((size_t)N * 32);
  float*    Q      = (float*)alloc((size_t)N * 32);
  float*    S      = (float*)alloc((size_t)N * 16);
  float*    r      = (float*)alloc((size_t)N * 4);
  unsigned* keys   = (unsigned*)alloc((size_t)N * 4);
  double*   acc    = (double*)alloc(16);
  float*    stats  = (float*)alloc(8);
  unsigned* state  = (unsigned*)alloc(8);
  unsigned* hist   = (unsigned*)alloc(1024);
  unsigned* blkcnt = (unsigned*)alloc((size_t)NB * 4);
  unsigned* scanbf = (unsigned*)alloc((size_t)NB * 4);
  int*      rowptr = (int*)alloc((size_t)(N + 1) * 4);
  int*      cursor = (int*)alloc((size_t)N * 4);
  int*      cnt    = (int*)alloc((size_t)N * 4);
  int*      bsum   = (int*)alloc(2048);
  int2*     adj    = (int2*)alloc((size_t)E * 8);
  size_t need = (size_t)(p - (char*)d_ws);

  dim3 B(BS);
  int genb = (E + BS - 1) / BS;                       // edge-parallel
  int ggrp = (int)(((size_t)N * GPN + BS - 1) / BS);  // 16-lane-per-node
  dim3 GE(genb), GG(ggrp), GN(NB);

  if (need <= ws_size) {
    // =========== CSR gather path ===========
    hipMemsetAsync(cnt, 0, (size_t)N * 4, stream);
    hipMemsetAsync(acc, 0, 16, stream);
    hipMemsetAsync(hist, 0, 1024, stream);

    k_count<<<GE, B, 0, stream>>>(dst, cnt, E);
    k_scanA<<<dim3(NB2), B, 0, stream>>>(cnt, bsum, N);
    k_scanB<<<dim3(1), B, 0, stream>>>(bsum, NB2);
    k_scanC<<<dim3(NB2), B, 0, stream>>>(cnt, bsum, rowptr, cursor, N, E);
    k_place<<<GE, B, 0, stream>>>(src, dst, attr, cursor, adj, E);
    k_degdis<<<GG, B, 0, stream>>>(rowptr, adj, dis, N);
    k_scalecsr<<<GG, B, 0, stream>>>(rowptr, adj, dis, N);

    // layer 1 (scalar props, y fused into last)
    k_gprop1<<<GG, B, 0, stream>>>(rowptr, adj, x, (const float*)nullptr, h1, N);
    k_gprop1<<<GG, B, 0, stream>>>(rowptr, adj, h1, (const float*)nullptr, h2, N);
    k_gprop1_y<<<GG, B, 0, stream>>>(rowptr, adj, h2, x, h1, W1, b1, y, N);

    // layer 2 (Horner; matvec bases fused into props; proj fused into last)
    k_matvec8<<<GN, B, 0, stream>>>(y, W2 + 3 * 64, P, N);
    k_gprop8<<<GG, B, 0, stream>>>(rowptr, adj, P, y, W2 + 2 * 64, Q, N);
    k_gprop8<<<GG, B, 0, stream>>>(rowptr, adj, Q, y, W2 + 1 * 64, P, N);
    k_gprop8_fin<<<GG, B, 0, stream>>>(rowptr, adj, P, y, W2, b2, W3, S, N);

    // layer 3 (scalar props, in-place Horner bases)
    k_gprop1<<<GG, B, 0, stream>>>(rowptr, adj, S + 3 * (size_t)N, S + 2 * (size_t)N, S + 2 * (size_t)N, N);
    k_gprop1<<<GG, B, 0, stream>>>(rowptr, adj, S + 2 * (size_t)N, S + 1 * (size_t)N, S + 1 * (size_t)N, N);
    k_gprop1<<<GG, B, 0, stream>>>(rowptr, adj, S + 1 * (size_t)N, S + 0 * (size_t)N, S + 0 * (size_t)N, N);

    // stats + normalize
    k_relusum<<<GN, B, 0, stream>>>(S, b3, r, acc, N);
    k_mean<<<dim3(1), dim3(1), 0, stream>>>(acc, stats, N);
    k_var<<<GN, B, 0, stream>>>(r, stats, acc, N);
    k_finstats<<<dim3(1), dim3(1), 0, stream>>>(acc, stats, N);
    k_normalize<<<GN, B, 0, stream>>>(r, stats, out, keys, N);

    // top-k radix select
    k_stateinit<<<dim3(1), dim3(1), 0, stream>>>(state, kp);
    for (int shift = 24; shift >= 0; shift -= 8) {
      k_hist<<<GN, B, 0, stream>>>(keys, N, state, hist, shift);
      k_select<<<dim3(1), dim3(1), 0, stream>>>(state, hist, shift);
    }
    k_mark<<<GN, B, 0, stream>>>(keys, N, state, out, blkcnt);
    k_scanP<<<dim3(1), B, 0, stream>>>(blkcnt, scanbf, NB);
    k_resolve<<<GN, B, 0, stream>>>(keys, N, state, scanbf, out);
  } else {
    // =========== fallback: round-1 atomic-scatter path ===========
    float* fws = (float*)d_ws;
    float* fdis = fws;
    float* fh1  = fws + (size_t)N;
    float* fh2  = fws + (size_t)2 * N;
    float* fh3  = fws + (size_t)3 * N;
    float* fy   = fws + (size_t)4 * N;
    float* fP   = fws + (size_t)12 * N;
    float* fQ   = fws + (size_t)20 * N;
    float* fS   = fws + (size_t)28 * N;
    float* fr   = fws + (size_t)32 * N;
    unsigned* fkeys = (unsigned*)(fws + (size_t)33 * N);
    char* small_ = (char*)(fws + (size_t)34 * N);
    double*   facc    = (double*)small_;
    float*    fstats  = (float*)(small_ + 16);
    unsigned* fstate  = (unsigned*)(small_ + 24);
    unsigned* fhist   = (unsigned*)(small_ + 32);
    unsigned* fblkcnt  = (unsigned*)(small_ + 32 + 1024);
    unsigned* fscanbf  = fblkcnt + NB;

    hipMemsetAsync(fws, 0, (size_t)4 * N * sizeof(float), stream);
    hipMemsetAsync(small_, 0, 32 + 1024, stream);

    int ge = (E + BS - 1) / BS; if (ge > 4096) ge = 4096;
    dim3 GEf(ge);

    k_deg<<<GEf, B, 0, stream>>>(dst, attr, fdis, E);
    k_dis<<<GN, B, 0, stream>>>(fdis, N);
    k_prop1<<<GEf, B, 0, stream>>>(src, dst, attr, fdis, x,   fh1, E);
    k_prop1<<<GEf, B, 0, stream>>>(src, dst, attr, fdis, fh1, fh2, E);
    k_prop1<<<GEf, B, 0, stream>>>(src, dst, attr, fdis, fh2, fh3, E);
    k_layer1<<<GN, B, 0, stream>>>(x, fh1, fh2, fh3, W1, b1, fy, N);
    k_matvec8<<<GN, B, 0, stream>>>(fy, W2 + 3 * 64, fP, N);
    k_matvec8<<<GN, B, 0, stream>>>(fy, W2 + 2 * 64, fQ, N);
    k_prop8<<<GEf, B, 0, stream>>>(src, dst, attr, fdis, fP, fQ, E);
    k_matvec8<<<GN, B, 0, stream>>>(fy, W2 + 1 * 64, fP, N);
    k_prop8<<<GEf, B, 0, stream>>>(src, dst, attr, fdis, fQ, fP, E);
    k_matvec8<<<GN, B, 0, stream>>>(fy, W2 + 0 * 64, fQ, N);
    k_prop8<<<GEf, B, 0, stream>>>(src, dst, attr, fdis, fP, fQ, E);
    k_layer3s<<<GN, B, 0, stream>>>(fQ, b2, W3, fS, N);
    k_prop1<<<GEf, B, 0, stream>>>(src, dst, attr, fdis, fS + 3 * (size_t)N, fS + 2 * (size_t)N, E);
    k_prop1<<<GEf, B, 0, stream>>>(src, dst, attr, fdis, fS + 2 * (size_t)N, fS + 1 * (size_t)N, E);
    k_prop1<<<GEf, B, 0, stream>>>(src, dst, attr, fdis, fS + 1 * (size_t)N, fS + 0 * (size_t)N, E);
    k_relusum<<<GN, B, 0, stream>>>(fS, b3, fr, facc, N);
    k_mean<<<dim3(1), dim3(1), 0, stream>>>(facc, fstats, N);
    k_var<<<GN, B, 0, stream>>>(fr, fstats, facc, N);
    k_finstats<<<dim3(1), dim3(1), 0, stream>>>(facc, fstats, N);
    k_normalize<<<GN, B, 0, stream>>>(fr, fstats, out, fkeys, N);
    k_stateinit<<<dim3(1), dim3(1), 0, stream>>>(fstate, kp);
    for (int shift = 24; shift >= 0; shift -= 8) {
      k_hist<<<GN, B, 0, stream>>>(fkeys, N, fstate, fhist, shift);
      k_select<<<dim3(1), dim3(1), 0, stream>>>(fstate, fhist, shift);
    }
    k_mark<<<GN, B, 0, stream>>>(fkeys, N, fstate, out, fblkcnt);
    k_scanP<<<dim3(1), B, 0, stream>>>(fblkcnt, fscanbf, NB);
    k_resolve<<<GN, B, 0, stream>>>(fkeys, N, fstate, fscanbf, out);
  }
}

// Round 3
// 684.674 us; speedup vs baseline: 14.9583x; 1.8898x over previous
//
#include <hip/hip_runtime.h>

#define BS 256
#define GPN 16      // lanes cooperating per node in gather props
#define NBLKB 512   // blocks in binning pass
#define BSH 9       // nodes per bucket = 512

static __device__ __forceinline__ float relu_(float v) { return fmaxf(v, 0.0f); }

// ======================= new CSR build (bucketed, no global atomics) =======================

// per-block per-bucket histogram of dst
__global__ void k_binhist(const int* __restrict__ dst, int* __restrict__ bcnt,
                          int E, int chunk, int nbuck) {
  __shared__ int h[1024];
  int b = blockIdx.x, t = threadIdx.x;
  for (int i = t; i < nbuck; i += BS) h[i] = 0;
  __syncthreads();
  int beg = b * chunk, end = min(E, beg + chunk);
  for (int e = beg + t; e < end; e += BS) atomicAdd(&h[dst[e] >> BSH], 1);
  __syncthreads();
  for (int i = t; i < nbuck; i += BS) bcnt[(size_t)i * NBLKB + b] = h[i];
}

// per bucket: exclusive scan of its NBLKB block counts (in place); total -> btot
__global__ void k_bucketscan(int* __restrict__ bcnt, int* __restrict__ btot) {
  __shared__ int sh[BS];
  int bkt = blockIdx.x, t = threadIdx.x;
  size_t base = (size_t)bkt * NBLKB;
  int c0 = bcnt[base + 2 * t], c1 = bcnt[base + 2 * t + 1];
  int s = c0 + c1;
  sh[t] = s; __syncthreads();
  for (int off = 1; off < BS; off <<= 1) {
    int add = (t >= off) ? sh[t - off] : 0; __syncthreads();
    sh[t] += add; __syncthreads();
  }
  int ex = sh[t] - s;
  bcnt[base + 2 * t]     = ex;
  bcnt[base + 2 * t + 1] = ex + c0;
  if (t == BS - 1) btot[bkt] = sh[t];
}

// exclusive scan of bucket totals -> bbase (1 block)
__global__ void k_basescan(const int* __restrict__ btot, int* __restrict__ bbase, int nbuck) {
  __shared__ int sh[BS];
  int t = threadIdx.x;
  int run = 0;
  for (int c = 0; c < nbuck; c += BS) {
    int i = c + t;
    int v = (i < nbuck) ? btot[i] : 0;
    sh[t] = v; __syncthreads();
    for (int off = 1; off < BS; off <<= 1) {
      int add = (t >= off) ? sh[t - off] : 0; __syncthreads();
      sh[t] += add; __syncthreads();
    }
    if (i < nbuck) bbase[i] = run + sh[t] - v;
    run += sh[BS - 1];
    __syncthreads();
  }
}

// bin edges into bucket-contiguous bed[] = {(d_local<<17)|src, |attr|}; LDS cursors only
__global__ void k_bin(const int* __restrict__ src, const int* __restrict__ dst,
                      const float* __restrict__ attr, const int* __restrict__ bcnt,
                      const int* __restrict__ bbase, int2* __restrict__ bed,
                      int E, int chunk, int nbuck) {
  __shared__ int cur[1024];
  int b = blockIdx.x, t = threadIdx.x;
  for (int i = t; i < nbuck; i += BS)
    cur[i] = bbase[i] + bcnt[(size_t)i * NBLKB + b];
  __syncthreads();
  int beg = b * chunk, end = min(E, beg + chunk);
  for (int e = beg + t; e < end; e += BS) {
    int d = dst[e];
    int bkt = d >> BSH;
    int pos = atomicAdd(&cur[bkt], 1);
    unsigned packed = ((unsigned)(d & ((1 << BSH) - 1)) << 17) | (unsigned)src[e];
    bed[pos] = make_int2((int)packed, __float_as_int(fabsf(attr[e])));
  }
}

// per bucket: per-node counts + degree + dis, all in LDS
__global__ void k_cntdeg(const int2* __restrict__ bed, const int* __restrict__ bbase,
                         const int* __restrict__ btot, int* __restrict__ cnt,
                         float* __restrict__ dis, int N) {
  __shared__ int   lc[1 << BSH];
  __shared__ float ld[1 << BSH];
  int bkt = blockIdx.x, t = threadIdx.x;
  for (int i = t; i < (1 << BSH); i += BS) { lc[i] = 0; ld[i] = 0.f; }
  __syncthreads();
  int beg = bbase[bkt], tot = btot[bkt];
  for (int i = t; i < tot; i += BS) {
    int2 rec = bed[beg + i];
    unsigned u = (unsigned)rec.x;
    int dl = (int)(u >> 17);
    atomicAdd(&lc[dl], 1);
    atomicAdd(&ld[dl], __int_as_float(rec.y));
  }
  __syncthreads();
  int nb = bkt << BSH;
  for (int i = t; i < (1 << BSH); i += BS) {
    int n = nb + i;
    if (n < N) {
      cnt[n] = lc[i];
      float dg = ld[i];
      dis[n] = (dg > 0.f) ? (1.0f / sqrtf(dg)) : 0.f;
    }
  }
}

// per bucket: scatter into CSR adj with fused weight scaling; LDS cursors only
__global__ void k_fill(const int2* __restrict__ bed, const int* __restrict__ bbase,
                       const int* __restrict__ btot, const int* __restrict__ rowptr,
                       const float* __restrict__ dis, int2* __restrict__ adj, int N) {
  __shared__ int   rcur[1 << BSH];
  __shared__ float dloc[1 << BSH];
  int bkt = blockIdx.x, t = threadIdx.x;
  int nb = bkt << BSH;
  for (int i = t; i < (1 << BSH); i += BS) {
    int n = nb + i;
    rcur[i] = (n < N) ? rowptr[n] : 0;
    dloc[i] = (n < N) ? dis[n] : 0.f;
  }
  __syncthreads();
  int beg = bbase[bkt], tot = btot[bkt];
  for (int i = t; i < tot; i += BS) {
    int2 rec = bed[beg + i];
    unsigned u = (unsigned)rec.x;
    int dl = (int)(u >> 17);
    int s  = (int)(u & 0x1FFFFu);
    float w = __int_as_float(rec.y) * dis[s] * dloc[dl];
    int pos = atomicAdd(&rcur[dl], 1);
    adj[pos] = make_int2(s, __float_as_int(w));
  }
}

// ======================= rowptr scan =======================

__global__ void k_scanA(const int* __restrict__ cnt, int* __restrict__ bsum, int N) {
  __shared__ int sh[BS];
  int t = threadIdx.x;
  int base = blockIdx.x * 1024;
  int s = 0;
#pragma unroll
  for (int j = 0; j < 4; ++j) { int i = base + t * 4 + j; s += (i < N) ? cnt[i] : 0; }
  sh[t] = s; __syncthreads();
  for (int off = 128; off; off >>= 1) { if (t < off) sh[t] += sh[t + off]; __syncthreads(); }
  if (t == 0) bsum[blockIdx.x] = sh[0];
}

__global__ void k_scanB(int* __restrict__ bsum, int NB2) {
  __shared__ int sh[BS];
  int t = threadIdx.x;
  int v = (t < NB2) ? bsum[t] : 0;
  sh[t] = v; __syncthreads();
  for (int off = 1; off < BS; off <<= 1) {
    int add = (t >= off) ? sh[t - off] : 0; __syncthreads();
    sh[t] += add; __syncthreads();
  }
  if (t < NB2) bsum[t] = sh[t] - v;
}

__global__ void k_scanC(const int* __restrict__ cnt, const int* __restrict__ bsum,
                        int* __restrict__ rowptr, int* __restrict__ cursor, int N, int E) {
  __shared__ int sh[BS];
  int b = blockIdx.x, t = threadIdx.x;
  int base = b * 1024;
  int c[4]; int s = 0;
#pragma unroll
  for (int j = 0; j < 4; ++j) { int i = base + t * 4 + j; c[j] = (i < N) ? cnt[i] : 0; s += c[j]; }
  sh[t] = s; __syncthreads();
  for (int off = 1; off < BS; off <<= 1) {
    int add = (t >= off) ? sh[t - off] : 0; __syncthreads();
    sh[t] += add; __syncthreads();
  }
  int run = sh[t] - s + bsum[b];
#pragma unroll
  for (int j = 0; j < 4; ++j) {
    int i = base + t * 4 + j;
    if (i < N) { rowptr[i] = run; if (cursor) cursor[i] = run; run += c[j]; }
  }
  if (b == 0 && t == 0) rowptr[N] = E;
}

// ======================= mid-fallback CSR build (round-2, global atomics) =======================

__global__ void k_count(const int* __restrict__ dst, int* __restrict__ cnt, int E) {
  int e = blockIdx.x * blockDim.x + threadIdx.x;
  if (e < E) atomicAdd(&cnt[dst[e]], 1);
}

__global__ void k_place(const int* __restrict__ src, const int* __restrict__ dst,
                        const float* __restrict__ attr, int* __restrict__ cursor,
                        int2* __restrict__ adj, int E) {
  int e = blockIdx.x * blockDim.x + threadIdx.x;
  if (e >= E) return;
  int d = dst[e];
  int pos = atomicAdd(&cursor[d], 1);
  adj[pos] = make_int2(src[e], __float_as_int(fabsf(attr[e])));
}

__global__ void k_degdis(const int* __restrict__ rowptr, const int2* __restrict__ adj,
                         float* __restrict__ dis, int N) {
  int g = (blockIdx.x * blockDim.x + threadIdx.x) / GPN;
  int l = threadIdx.x & (GPN - 1);
  if (g >= N) return;
  int beg = rowptr[g], end = rowptr[g + 1];
  float s = 0.0f;
  for (int e = beg + l; e < end; e += GPN) s += __int_as_float(adj[e].y);
#pragma unroll
  for (int off = 8; off; off >>= 1) s += __shfl_xor(s, off, GPN);
  if (l == 0) dis[g] = (s > 0.0f) ? (1.0f / sqrtf(s)) : 0.0f;
}

__global__ void k_scalecsr(const int* __restrict__ rowptr, int2* adj,
                           const float* __restrict__ dis, int N) {
  int g = (blockIdx.x * blockDim.x + threadIdx.x) / GPN;
  int l = threadIdx.x & (GPN - 1);
  if (g >= N) return;
  float dn = dis[g];
  int beg = rowptr[g], end = rowptr[g + 1];
  for (int e = beg + l; e < end; e += GPN) {
    int2 sw = adj[e];
    float w = __int_as_float(sw.y) * dis[sw.x] * dn;
    adj[e] = make_int2(sw.x, __float_as_int(w));
  }
}

// ======================= gather props =======================

__global__ void k_gprop1(const int* __restrict__ rowptr, const int2* __restrict__ adj,
                         const float* __restrict__ hin, const float* __restrict__ base,
                         float* __restrict__ hout, int N) {
  int g = (blockIdx.x * blockDim.x + threadIdx.x) / GPN;
  int l = threadIdx.x & (GPN - 1);
  if (g >= N) return;
  int beg = rowptr[g], end = rowptr[g + 1];
  float acc = 0.0f;
  for (int e = beg + l; e < end; e += GPN) {
    int2 sw = adj[e];
    acc += __int_as_float(sw.y) * hin[sw.x];
  }
#pragma unroll
  for (int off = 8; off; off >>= 1) acc += __shfl_xor(acc, off, GPN);
  if (l == 0) hout[g] = (base ? base[g] : 0.0f) + acc;
}

__global__ void k_gprop1_y(const int* __restrict__ rowptr, const int2* __restrict__ adj,
                           const float* __restrict__ h2, const float* __restrict__ x,
                           const float* __restrict__ h1, const float* __restrict__ W1,
                           const float* __restrict__ b1, float* __restrict__ y, int N) {
  int g = (blockIdx.x * blockDim.x + threadIdx.x) / GPN;
  int l = threadIdx.x & (GPN - 1);
  if (g >= N) return;
  int beg = rowptr[g], end = rowptr[g + 1];
  float acc = 0.0f;
  for (int e = beg + l; e < end; e += GPN) {
    int2 sw = adj[e];
    acc += __int_as_float(sw.y) * h2[sw.x];
  }
#pragma unroll
  for (int off = 8; off; off >>= 1) acc += __shfl_xor(acc, off, GPN);
  if (l == 0) {
    float xv = x[g], a = h1[g], b = h2[g], c = acc;
    float o[8];
#pragma unroll
    for (int j = 0; j < 8; ++j)
      o[j] = relu_(xv * W1[j] + a * W1[8 + j] + b * W1[16 + j] + c * W1[24 + j] + b1[j]);
    float4* op = (float4*)(y + (size_t)g * 8);
    op[0] = make_float4(o[0], o[1], o[2], o[3]);
    op[1] = make_float4(o[4], o[5], o[6], o[7]);
  }
}

__global__ void k_gprop8(const int* __restrict__ rowptr, const int2* __restrict__ adj,
                         const float* __restrict__ hin, const float* __restrict__ y,
                         const float* __restrict__ W, float* __restrict__ hout, int N) {
  int g = (blockIdx.x * blockDim.x + threadIdx.x) / GPN;
  int l = threadIdx.x & (GPN - 1);
  if (g >= N) return;
  int beg = rowptr[g], end = rowptr[g + 1];
  float a0=0,a1=0,a2=0,a3=0,a4=0,a5=0,a6=0,a7=0;
  for (int e = beg + l; e < end; e += GPN) {
    int2 sw = adj[e];
    float w = __int_as_float(sw.y);
    const float4* hp = (const float4*)(hin + (size_t)sw.x * 8);
    float4 u = hp[0], v = hp[1];
    a0 += w*u.x; a1 += w*u.y; a2 += w*u.z; a3 += w*u.w;
    a4 += w*v.x; a5 += w*v.y; a6 += w*v.z; a7 += w*v.w;
  }
#pragma unroll
  for (int off = 8; off; off >>= 1) {
    a0 += __shfl_xor(a0, off, GPN); a1 += __shfl_xor(a1, off, GPN);
    a2 += __shfl_xor(a2, off, GPN); a3 += __shfl_xor(a3, off, GPN);
    a4 += __shfl_xor(a4, off, GPN); a5 += __shfl_xor(a5, off, GPN);
    a6 += __shfl_xor(a6, off, GPN); a7 += __shfl_xor(a7, off, GPN);
  }
  if (l == 0) {
    const float4* yp = (const float4*)(y + (size_t)g * 8);
    float4 u = yp[0], v = yp[1];
    float yi[8] = {u.x, u.y, u.z, u.w, v.x, v.y, v.z, v.w};
    float acc[8] = {a0, a1, a2, a3, a4, a5, a6, a7};
    float o[8];
#pragma unroll
    for (int j = 0; j < 8; ++j) {
      float s = acc[j];
#pragma unroll
      for (int i = 0; i < 8; ++i) s += yi[i] * W[i * 8 + j];
      o[j] = s;
    }
    float4* op = (float4*)(hout + (size_t)g * 8);
    op[0] = make_float4(o[0], o[1], o[2], o[3]);
    op[1] = make_float4(o[4], o[5], o[6], o[7]);
  }
}

__global__ void k_gprop8_fin(const int* __restrict__ rowptr, const int2* __restrict__ adj,
                             const float* __restrict__ hin, const float* __restrict__ y,
                             const float* __restrict__ W0, const float* __restrict__ b2,
                             const float* __restrict__ W3, float* __restrict__ S, int N) {
  int g = (blockIdx.x * blockDim.x + threadIdx.x) / GPN;
  int l = threadIdx.x & (GPN - 1);
  if (g >= N) return;
  int beg = rowptr[g], end = rowptr[g + 1];
  float a0=0,a1=0,a2=0,a3=0,a4=0,a5=0,a6=0,a7=0;
  for (int e = beg + l; e < end; e += GPN) {
    int2 sw = adj[e];
    float w = __int_as_float(sw.y);
    const float4* hp = (const float4*)(hin + (size_t)sw.x * 8);
    float4 u = hp[0], v = hp[1];
    a0 += w*u.x; a1 += w*u.y; a2 += w*u.z; a3 += w*u.w;
    a4 += w*v.x; a5 += w*v.y; a6 += w*v.z; a7 += w*v.w;
  }
#pragma unroll
  for (int off = 8; off; off >>= 1) {
    a0 += __shfl_xor(a0, off, GPN); a1 += __shfl_xor(a1, off, GPN);
    a2 += __shfl_xor(a2, off, GPN); a3 += __shfl_xor(a3, off, GPN);
    a4 += __shfl_xor(a4, off, GPN); a5 += __shfl_xor(a5, off, GPN);
    a6 += __shfl_xor(a6, off, GPN); a7 += __shfl_xor(a7, off, GPN);
  }
  if (l == 0) {
    const float4* yp = (const float4*)(y + (size_t)g * 8);
    float4 u = yp[0], v = yp[1];
    float yi[8] = {u.x, u.y, u.z, u.w, v.x, v.y, v.z, v.w};
    float acc[8] = {a0, a1, a2, a3, a4, a5, a6, a7};
    float z[8];
#pragma unroll
    for (int j = 0; j < 8; ++j) {
      float s = acc[j];
#pragma unroll
      for (int i = 0; i < 8; ++i) s += yi[i] * W0[i * 8 + j];
      z[j] = relu_(s + b2[j]);
    }
#pragma unroll
    for (int i = 0; i < 4; ++i) {
      float s = 0.0f;
#pragma unroll
      for (int j = 0; j < 8; ++j) s += z[j] * W3[i * 8 + j];
      S[(size_t)i * N + g] = s;
    }
  }
}

// ======================= node kernels =======================

__global__ void k_matvec8(const float* __restrict__ y, const float* __restrict__ W,
                          float* __restrict__ out, int N) {
  int n = blockIdx.x * blockDim.x + threadIdx.x;
  if (n >= N) return;
  const float4* yp = (const float4*)(y + (size_t)n * 8);
  float4 a = yp[0], b = yp[1];
  float yi[8] = {a.x, a.y, a.z, a.w, b.x, b.y, b.z, b.w};
  float o[8];
#pragma unroll
  for (int j = 0; j < 8; ++j) {
    float s = 0.0f;
#pragma unroll
    for (int i = 0; i < 8; ++i) s += yi[i] * W[i * 8 + j];
    o[j] = s;
  }
  float4* op = (float4*)(out + (size_t)n * 8);
  op[0] = make_float4(o[0], o[1], o[2], o[3]);
  op[1] = make_float4(o[4], o[5], o[6], o[7]);
}

__global__ void k_relusum(const float* __restrict__ v3, const float* __restrict__ b3,
                          float* __restrict__ r, double* __restrict__ acc, int N) {
  int n = blockIdx.x * blockDim.x + threadIdx.x;
  double v = 0.0;
  if (n < N) { float rv = relu_(v3[n] + b3[0]); r[n] = rv; v = (double)rv; }
#pragma unroll
  for (int off = 32; off; off >>= 1) v += __shfl_down(v, off);
  if ((threadIdx.x & 63) == 0) atomicAdd(acc, v);
}

__global__ void k_mean(const double* __restrict__ acc, float* __restrict__ stats, int N) {
  stats[0] = (float)(acc[0] / (double)N);
}

__global__ void k_var(const float* __restrict__ r, const float* __restrict__ stats,
                      double* __restrict__ acc, int N) {
  int n = blockIdx.x * blockDim.x + threadIdx.x;
  double v = 0.0;
  if (n < N) { float d = r[n] - stats[0]; v = (double)d * (double)d; }
#pragma unroll
  for (int off = 32; off; off >>= 1) v += __shfl_down(v, off);
  if ((threadIdx.x & 63) == 0) atomicAdd(acc + 1, v);
}

__global__ void k_finstats(const double* __restrict__ acc, float* __restrict__ stats, int N) {
  double var = acc[1] / (double)N;
  stats[1] = (float)(1.0 / sqrt(var + 1e-5));
}

__global__ void k_normalize(const float* __restrict__ r, const float* __restrict__ stats,
                            float* __restrict__ out, unsigned* __restrict__ keys, int N) {
  int n = blockIdx.x * blockDim.x + threadIdx.x;
  if (n >= N) return;
  float xv = (r[n] - stats[0]) * stats[1];
  out[2 * (size_t)n] = xv;
  unsigned u = __float_as_uint(xv);
  u = (u & 0x80000000u) ? ~u : (u | 0x80000000u);
  keys[n] = u;
}

__global__ void k_stateinit(unsigned* __restrict__ state, const int* __restrict__ kp) {
  state[0] = 0u;
  state[1] = (unsigned)kp[0];
}

__global__ void k_hist(const unsigned* __restrict__ keys, int N,
                       const unsigned* __restrict__ state, unsigned* __restrict__ hist,
                       int shift) {
  __shared__ unsigned sh[256];
  sh[threadIdx.x] = 0;
  __syncthreads();
  unsigned prefix = state[0];
  unsigned hmask = (shift >= 24) ? 0u : (0xFFFFFFFFu << (shift + 8));
  int stride = gridDim.x * blockDim.x;
  for (int n = blockIdx.x * blockDim.x + threadIdx.x; n < N; n += stride) {
    unsigned kk = keys[n];
    if ((kk & hmask) == (prefix & hmask)) atomicAdd(&sh[(kk >> shift) & 255u], 1u);
  }
  __syncthreads();
  atomicAdd(&hist[threadIdx.x], sh[threadIdx.x]);
}

__global__ void k_select(unsigned* __restrict__ state, unsigned* __restrict__ hist, int shift) {
  unsigned rem = state[1];
  unsigned cum = 0;
  int b = 255;
  for (; b >= 0; --b) {
    unsigned c = hist[b];
    if (cum + c >= rem) break;
    cum += c;
  }
  if (b < 0) b = 0;
  state[0] |= ((unsigned)b) << shift;
  state[1] = rem - cum;
  for (int i = 0; i < 256; ++i) hist[i] = 0;
}

__global__ void k_mark(const unsigned* __restrict__ keys, int N,
                       const unsigned* __restrict__ state, float* __restrict__ out,
                       unsigned* __restrict__ blkcnt) {
  unsigned T = state[0];
  int n = blockIdx.x * 256 + threadIdx.x;
  int eq = 0;
  __shared__ int sh;
  if (threadIdx.x == 0) sh = 0;
  __syncthreads();
  if (n < N) {
    unsigned kk = keys[n];
    out[2 * (size_t)n + 1] = (kk > T) ? 1.0f : 0.0f;
    eq = (kk == T);
  }
  if (eq) atomicAdd(&sh, 1);
  __syncthreads();
  if (threadIdx.x == 0) blkcnt[blockIdx.x] = (unsigned)sh;
}

__global__ void k_scanP(const unsigned* __restrict__ blkcnt, unsigned* __restrict__ scanbuf, int NB) {
  __shared__ unsigned sh[BS];
  int t = threadIdx.x;
  unsigned c0 = (2 * t < NB) ? blkcnt[2 * t] : 0u;
  unsigned c1 = (2 * t + 1 < NB) ? blkcnt[2 * t + 1] : 0u;
  unsigned s = c0 + c1;
  sh[t] = s; __syncthreads();
  for (int off = 1; off < BS; off <<= 1) {
    unsigned add = (t >= off) ? sh[t - off] : 0u; __syncthreads();
    sh[t] += add; __syncthreads();
  }
  unsigned ex = sh[t] - s;
  if (2 * t < NB) scanbuf[2 * t] = ex;
  if (2 * t + 1 < NB) scanbuf[2 * t + 1] = ex + c0;
}

__global__ void k_resolve(const unsigned* __restrict__ keys, int N,
                          const unsigned* __restrict__ state,
                          const unsigned* __restrict__ scanbuf, float* __restrict__ out) {
  unsigned T = state[0];
  unsigned m = state[1];
  int n = blockIdx.x * 256 + threadIdx.x;
  if (n >= N) return;
  if (keys[n] != T) return;
  unsigned rank = scanbuf[blockIdx.x];
  int base = blockIdx.x * 256;
  for (int j = base; j < n; ++j) rank += (keys[j] == T);
  out[2 * (size_t)n + 1] = (rank < m) ? 1.0f : 0.0f;
}

// ======================= launcher =======================

extern "C" void kernel_launch(void* const* d_in, const int* in_sizes, int n_in,
                              void* d_out, int out_size, void* d_ws, size_t ws_size,
                              hipStream_t stream) {
  const float* x    = (const float*)d_in[0];
  const int*   ei   = (const int*)d_in[1];
  const float* attr = (const float*)d_in[2];
  const int*   kp   = (const int*)d_in[3];
  const float* W1   = (const float*)d_in[4];
  const float* b1   = (const float*)d_in[5];
  const float* W2   = (const float*)d_in[6];
  const float* b2   = (const float*)d_in[7];
  const float* W3   = (const float*)d_in[8];
  const float* b3   = (const float*)d_in[9];
  const int N = in_sizes[0];
  const int E = in_sizes[2];
  const int* src = ei;
  const int* dst = ei + E;
  float* out = (float*)d_out;
  const int NB    = (N + 255) / 256;
  const int NB2   = (N + 1023) / 1024;
  const int NBUCK = (N + (1 << BSH) - 1) >> BSH;
  const int chunk = (E + NBLKB - 1) / NBLKB;

  // ---- bump allocator over d_ws ----
  char* p = (char*)d_ws;
  auto alloc = [&](size_t bytes) -> char* {
    char* r = p; p += (bytes + 255) & ~(size_t)255; return r;
  };
  float*    dis    = (float*)alloc((size_t)N * 4);
  float*    h1     = (float*)alloc((size_t)N * 4);
  float*    h2     = (float*)alloc((size_t)N * 4);
  float*    y      = (float*)alloc((size_t)N * 32);
  float*    P      = (float*)alloc((size_t)N * 32);
  float*    Q      = (float*)alloc((size_t)N * 32);
  float*    S      = (float*)alloc((size_t)N * 16);
  float*    r      = (float*)alloc((size_t)N * 4);
  unsigned* keys   = (unsigned*)alloc((size_t)N * 4);
  double*   acc    = (double*)alloc(16);
  float*    stats  = (float*)alloc(8);
  unsigned* state  = (unsigned*)alloc(8);
  unsigned* hist   = (unsigned*)alloc(1024);
  unsigned* blkcnt = (unsigned*)alloc((size_t)NB * 4);
  unsigned* scanbf = (unsigned*)alloc((size_t)NB * 4);
  int*      rowptr = (int*)alloc((size_t)(N + 1) * 4);
  int*      cursor = (int*)alloc((size_t)N * 4);
  int*      cnt    = (int*)alloc((size_t)N * 4);
  int*      bsum   = (int*)alloc(2048);
  int2*     adj    = (int2*)alloc((size_t)E * 8);
  size_t need_mid = (size_t)(p - (char*)d_ws);
  int2*     bed    = (int2*)alloc((size_t)E * 8);
  int*      bcnt   = (int*)alloc((size_t)NBUCK * NBLKB * 4);
  int*      btot   = (int*)alloc(4096);
  int*      bbase  = (int*)alloc(4096);
  size_t need_new = (size_t)(p - (char*)d_ws);

  dim3 B(BS);
  int genb = (E + BS - 1) / BS;
  int ggrp = (int)(((size_t)N * GPN + BS - 1) / BS);
  dim3 GE(genb), GG(ggrp), GN(NB), GB(NBUCK);

  bool use_new = (need_new <= ws_size) && (N <= 131072);

  hipMemsetAsync(acc, 0, 16, stream);
  hipMemsetAsync(hist, 0, 1024, stream);

  if (use_new) {
    // =========== bucketed CSR build, no global atomics ===========
    k_binhist<<<dim3(NBLKB), B, 0, stream>>>(dst, bcnt, E, chunk, NBUCK);
    k_bucketscan<<<GB, B, 0, stream>>>(bcnt, btot);
    k_basescan<<<dim3(1), B, 0, stream>>>(btot, bbase, NBUCK);
    k_bin<<<dim3(NBLKB), B, 0, stream>>>(src, dst, attr, bcnt, bbase, bed, E, chunk, NBUCK);
    k_cntdeg<<<GB, B, 0, stream>>>(bed, bbase, btot, cnt, dis, N);
    k_scanA<<<dim3(NB2), B, 0, stream>>>(cnt, bsum, N);
    k_scanB<<<dim3(1), B, 0, stream>>>(bsum, NB2);
    k_scanC<<<dim3(NB2), B, 0, stream>>>(cnt, bsum, rowptr, (int*)nullptr, N, E);
    k_fill<<<GB, B, 0, stream>>>(bed, bbase, btot, rowptr, dis, adj, N);
  } else {
    // =========== round-2 CSR build (global atomics) ===========
    hipMemsetAsync(cnt, 0, (size_t)N * 4, stream);
    k_count<<<GE, B, 0, stream>>>(dst, cnt, E);
    k_scanA<<<dim3(NB2), B, 0, stream>>>(cnt, bsum, N);
    k_scanB<<<dim3(1), B, 0, stream>>>(bsum, NB2);
    k_scanC<<<dim3(NB2), B, 0, stream>>>(cnt, bsum, rowptr, cursor, N, E);
    k_place<<<GE, B, 0, stream>>>(src, dst, attr, cursor, adj, E);
    k_degdis<<<GG, B, 0, stream>>>(rowptr, adj, dis, N);
    k_scalecsr<<<GG, B, 0, stream>>>(rowptr, adj, dis, N);
  }

  // layer 1 (scalar props, y fused into last)
  k_gprop1<<<GG, B, 0, stream>>>(rowptr, adj, x, (const float*)nullptr, h1, N);
  k_gprop1<<<GG, B, 0, stream>>>(rowptr, adj, h1, (const float*)nullptr, h2, N);
  k_gprop1_y<<<GG, B, 0, stream>>>(rowptr, adj, h2, x, h1, W1, b1, y, N);

  // layer 2 (Horner; matvec bases fused into props; proj fused into last)
  k_matvec8<<<GN, B, 0, stream>>>(y, W2 + 3 * 64, P, N);
  k_gprop8<<<GG, B, 0, stream>>>(rowptr, adj, P, y, W2 + 2 * 64, Q, N);
  k_gprop8<<<GG, B, 0, stream>>>(rowptr, adj, Q, y, W2 + 1 * 64, P, N);
  k_gprop8_fin<<<GG, B, 0, stream>>>(rowptr, adj, P, y, W2, b2, W3, S, N);

  // layer 3 (scalar props, in-place Horner bases)
  k_gprop1<<<GG, B, 0, stream>>>(rowptr, adj, S + 3 * (size_t)N, S + 2 * (size_t)N, S + 2 * (size_t)N, N);
  k_gprop1<<<GG, B, 0, stream>>>(rowptr, adj, S + 2 * (size_t)N, S + 1 * (size_t)N, S + 1 * (size_t)N, N);
  k_gprop1<<<GG, B, 0, stream>>>(rowptr, adj, S + 1 * (size_t)N, S + 0 * (size_t)N, S + 0 * (size_t)N, N);

  // stats + normalize
  k_relusum<<<GN, B, 0, stream>>>(S, b3, r, acc, N);
  k_mean<<<dim3(1), dim3(1), 0, stream>>>(acc, stats, N);
  k_var<<<GN, B, 0, stream>>>(r, stats, acc, N);
  k_finstats<<<dim3(1), dim3(1), 0, stream>>>(acc, stats, N);
  k_normalize<<<GN, B, 0, stream>>>(r, stats, out, keys, N);

  // top-k radix select
  k_stateinit<<<dim3(1), dim3(1), 0, stream>>>(state, kp);
  for (int shift = 24; shift >= 0; shift -= 8) {
    k_hist<<<GN, B, 0, stream>>>(keys, N, state, hist, shift);
    k_select<<<dim3(1), dim3(1), 0, stream>>>(state, hist, shift);
  }
  k_mark<<<GN, B, 0, stream>>>(keys, N, state, out, blkcnt);
  k_scanP<<<dim3(1), B, 0, stream>>>(blkcnt, scanbf, NB);
  k_resolve<<<GN, B, 0, stream>>>(keys, N, state, scanbf, out);
}

// Round 4
// 615.294 us; speedup vs baseline: 16.6450x; 1.1128x over previous
//
#include <hip/hip_runtime.h>

#define BS 256
#define GPN 16       // lanes per node in gather props
#define NBLKB 1024   // blocks in binning pass (VPT in bucketscan = NBLKB/BS = 4)
#define BSH 8        // nodes per bucket = 256

static __device__ __forceinline__ float relu_(float v) { return fmaxf(v, 0.0f); }

// ======================= bucketed CSR build (no global atomics) =======================

__global__ void k_binhist(const int* __restrict__ dst, int* __restrict__ bcnt,
                          int E, int chunk, int nbuck) {
  __shared__ int h[1024];
  int b = blockIdx.x, t = threadIdx.x;
  for (int i = t; i < nbuck; i += BS) h[i] = 0;
  __syncthreads();
  int beg = b * chunk, end = min(E, beg + chunk);
  for (int e = beg + t; e < end; e += BS) atomicAdd(&h[dst[e] >> BSH], 1);
  __syncthreads();
  for (int i = t; i < nbuck; i += BS) bcnt[(size_t)i * NBLKB + b] = h[i];
}

// per bucket: exclusive scan of its NBLKB block counts (in place); total -> btot
__global__ void k_bucketscan(int* __restrict__ bcnt, int* __restrict__ btot) {
  __shared__ int sh[BS];
  int bkt = blockIdx.x, t = threadIdx.x;
  size_t base = (size_t)bkt * NBLKB;
  int c[4], s = 0;
#pragma unroll
  for (int j = 0; j < 4; ++j) { c[j] = bcnt[base + t * 4 + j]; s += c[j]; }
  sh[t] = s; __syncthreads();
  for (int off = 1; off < BS; off <<= 1) {
    int add = (t >= off) ? sh[t - off] : 0; __syncthreads();
    sh[t] += add; __syncthreads();
  }
  int run = sh[t] - s;
#pragma unroll
  for (int j = 0; j < 4; ++j) { bcnt[base + t * 4 + j] = run; run += c[j]; }
  if (t == BS - 1) btot[bkt] = run;
}

__global__ void k_basescan(const int* __restrict__ btot, int* __restrict__ bbase, int nbuck) {
  __shared__ int sh[BS];
  int t = threadIdx.x;
  int run = 0;
  for (int c = 0; c < nbuck; c += BS) {
    int i = c + t;
    int v = (i < nbuck) ? btot[i] : 0;
    sh[t] = v; __syncthreads();
    for (int off = 1; off < BS; off <<= 1) {
      int add = (t >= off) ? sh[t - off] : 0; __syncthreads();
      sh[t] += add; __syncthreads();
    }
    if (i < nbuck) bbase[i] = run + sh[t] - v;
    run += sh[BS - 1];
    __syncthreads();
  }
}

// bin edges into bucket-contiguous bed[] = {(d_local<<17)|src, |attr|}; LDS cursors only
__global__ void k_bin(const int* __restrict__ src, const int* __restrict__ dst,
                      const float* __restrict__ attr, const int* __restrict__ bcnt,
                      const int* __restrict__ bbase, int2* __restrict__ bed,
                      int E, int chunk, int nbuck) {
  __shared__ int cur[1024];
  int b = blockIdx.x, t = threadIdx.x;
  for (int i = t; i < nbuck; i += BS)
    cur[i] = bbase[i] + bcnt[(size_t)i * NBLKB + b];
  __syncthreads();
  int beg = b * chunk, end = min(E, beg + chunk);
  for (int e = beg + t; e < end; e += BS) {
    int d = dst[e];
    int bkt = d >> BSH;
    int pos = atomicAdd(&cur[bkt], 1);
    unsigned packed = ((unsigned)(d & ((1 << BSH) - 1)) << 17) | (unsigned)src[e];
    bed[pos] = make_int2((int)packed, __float_as_int(fabsf(attr[e])));
  }
}

// per bucket: per-node count, degree, dis, and xhat = dis*x
__global__ void k_cntdeg(const int2* __restrict__ bed, const int* __restrict__ bbase,
                         const int* __restrict__ btot, const float* __restrict__ x,
                         int* __restrict__ cnt, float* __restrict__ dis,
                         float* __restrict__ xhat, int N) {
  __shared__ int   lc[1 << BSH];
  __shared__ float ld[1 << BSH];
  int bkt = blockIdx.x, t = threadIdx.x;
  for (int i = t; i < (1 << BSH); i += BS) { lc[i] = 0; ld[i] = 0.f; }
  __syncthreads();
  int beg = bbase[bkt], tot = btot[bkt];
  for (int i = t; i < tot; i += BS) {
    int2 rec = bed[beg + i];
    int dl = (int)((unsigned)rec.x >> 17);
    atomicAdd(&lc[dl], 1);
    atomicAdd(&ld[dl], __int_as_float(rec.y));
  }
  __syncthreads();
  int nb = bkt << BSH;
  for (int i = t; i < (1 << BSH); i += BS) {
    int n = nb + i;
    if (n < N) {
      cnt[n] = lc[i];
      float dg = ld[i];
      float d = (dg > 0.f) ? (1.0f / sqrtf(dg)) : 0.f;
      dis[n] = d;
      xhat[n] = d * x[n];
    }
  }
}

// per bucket: scatter into CSR adj (raw weights); LDS cursors only
__global__ void k_fill(const int2* __restrict__ bed, const int* __restrict__ bbase,
                       const int* __restrict__ btot, const int* __restrict__ rowptr,
                       int2* __restrict__ adj, int N) {
  __shared__ int rcur[1 << BSH];
  int bkt = blockIdx.x, t = threadIdx.x;
  int nb = bkt << BSH;
  for (int i = t; i < (1 << BSH); i += BS) {
    int n = nb + i;
    rcur[i] = (n < N) ? rowptr[n] : 0;
  }
  __syncthreads();
  int beg = bbase[bkt], tot = btot[bkt];
  for (int i = t; i < tot; i += BS) {
    int2 rec = bed[beg + i];
    unsigned u = (unsigned)rec.x;
    int dl = (int)(u >> 17);
    int s  = (int)(u & 0x1FFFFu);
    int pos = atomicAdd(&rcur[dl], 1);
    adj[pos] = make_int2(s, rec.y);
  }
}

// ======================= rowptr scan =======================

__global__ void k_scanA(const int* __restrict__ cnt, int* __restrict__ bsum, int N) {
  __shared__ int sh[BS];
  int t = threadIdx.x;
  int base = blockIdx.x * 1024;
  int s = 0;
#pragma unroll
  for (int j = 0; j < 4; ++j) { int i = base + t * 4 + j; s += (i < N) ? cnt[i] : 0; }
  sh[t] = s; __syncthreads();
  for (int off = 128; off; off >>= 1) { if (t < off) sh[t] += sh[t + off]; __syncthreads(); }
  if (t == 0) bsum[blockIdx.x] = sh[0];
}

__global__ void k_scanB(int* __restrict__ bsum, int NB2) {
  __shared__ int sh[BS];
  int t = threadIdx.x;
  int v = (t < NB2) ? bsum[t] : 0;
  sh[t] = v; __syncthreads();
  for (int off = 1; off < BS; off <<= 1) {
    int add = (t >= off) ? sh[t - off] : 0; __syncthreads();
    sh[t] += add; __syncthreads();
  }
  if (t < NB2) bsum[t] = sh[t] - v;
}

__global__ void k_scanC(const int* __restrict__ cnt, const int* __restrict__ bsum,
                        int* __restrict__ rowptr, int* __restrict__ cursor, int N, int E) {
  __shared__ int sh[BS];
  int b = blockIdx.x, t = threadIdx.x;
  int base = b * 1024;
  int c[4]; int s = 0;
#pragma unroll
  for (int j = 0; j < 4; ++j) { int i = base + t * 4 + j; c[j] = (i < N) ? cnt[i] : 0; s += c[j]; }
  sh[t] = s; __syncthreads();
  for (int off = 1; off < BS; off <<= 1) {
    int add = (t >= off) ? sh[t - off] : 0; __syncthreads();
    sh[t] += add; __syncthreads();
  }
  int run = sh[t] - s + bsum[b];
#pragma unroll
  for (int j = 0; j < 4; ++j) {
    int i = base + t * 4 + j;
    if (i < N) { rowptr[i] = run; if (cursor) cursor[i] = run; run += c[j]; }
  }
  if (b == 0 && t == 0) rowptr[N] = E;
}

// ======================= fallback CSR build (global atomics) =======================

__global__ void k_count(const int* __restrict__ dst, int* __restrict__ cnt, int E) {
  int e = blockIdx.x * blockDim.x + threadIdx.x;
  if (e < E) atomicAdd(&cnt[dst[e]], 1);
}

__global__ void k_place(const int* __restrict__ src, const int* __restrict__ dst,
                        const float* __restrict__ attr, int* __restrict__ cursor,
                        int2* __restrict__ adj, int E) {
  int e = blockIdx.x * blockDim.x + threadIdx.x;
  if (e >= E) return;
  int d = dst[e];
  int pos = atomicAdd(&cursor[d], 1);
  adj[pos] = make_int2(src[e], __float_as_int(fabsf(attr[e])));
}

__global__ void k_degdis(const int* __restrict__ rowptr, const int2* __restrict__ adj,
                         const float* __restrict__ x, float* __restrict__ dis,
                         float* __restrict__ xhat, int N) {
  int g = (blockIdx.x * blockDim.x + threadIdx.x) / GPN;
  int l = threadIdx.x & (GPN - 1);
  if (g >= N) return;
  int beg = rowptr[g], end = rowptr[g + 1];
  float s = 0.0f;
  for (int e = beg + l; e < end; e += GPN) s += __int_as_float(adj[e].y);
#pragma unroll
  for (int off = 8; off; off >>= 1) s += __shfl_xor(s, off, GPN);
  if (l == 0) {
    float d = (s > 0.0f) ? (1.0f / sqrtf(s)) : 0.0f;
    dis[g] = d;
    xhat[g] = d * x[g];
  }
}

// ======================= u-space gather props =======================
// uhat = dis*h; per-edge weight stays raw |attr|; acc = sum w*uhat[src].

// h = dis*acc; uout = dis*h   (layer-1 props 1,2)
__global__ void k_gp1_uh(const int* __restrict__ rowptr, const int2* __restrict__ adj,
                         const float* __restrict__ uin, const float* __restrict__ dis,
                         float* __restrict__ hout, float* __restrict__ uout, int N) {
  int g = (blockIdx.x * blockDim.x + threadIdx.x) / GPN;
  int l = threadIdx.x & (GPN - 1);
  if (g >= N) return;
  int beg = rowptr[g], end = rowptr[g + 1];
  float acc = 0.0f;
  for (int e = beg + l; e < end; e += GPN) {
    int2 sw = adj[e];
    acc += __int_as_float(sw.y) * uin[sw.x];
  }
#pragma unroll
  for (int off = 8; off; off >>= 1) acc += __shfl_xor(acc, off, GPN);
  if (l == 0) {
    float d = dis[g];
    float h = d * acc;
    hout[g] = h;
    uout[g] = d * h;
  }
}

// layer-1 prop 3 fused with y-epilogue and Phat = dis*(y @ W23)
__global__ void k_gp1_y(const int* __restrict__ rowptr, const int2* __restrict__ adj,
                        const float* __restrict__ u2, const float* __restrict__ x,
                        const float* __restrict__ h1, const float* __restrict__ h2,
                        const float* __restrict__ dis, const float* __restrict__ W1,
                        const float* __restrict__ b1, const float* __restrict__ W23,
                        float* __restrict__ y, float* __restrict__ Phat, int N) {
  int g = (blockIdx.x * blockDim.x + threadIdx.x) / GPN;
  int l = threadIdx.x & (GPN - 1);
  if (g >= N) return;
  int beg = rowptr[g], end = rowptr[g + 1];
  float acc = 0.0f;
  for (int e = beg + l; e < end; e += GPN) {
    int2 sw = adj[e];
    acc += __int_as_float(sw.y) * u2[sw.x];
  }
#pragma unroll
  for (int off = 8; off; off >>= 1) acc += __shfl_xor(acc, off, GPN);
  if (l == 0) {
    float d = dis[g];
    float xv = x[g], a = h1[g], b = h2[g], c = d * acc;
    float o[8];
#pragma unroll
    for (int j = 0; j < 8; ++j)
      o[j] = relu_(xv * W1[j] + a * W1[8 + j] + b * W1[16 + j] + c * W1[24 + j] + b1[j]);
    float4* op = (float4*)(y + (size_t)g * 8);
    op[0] = make_float4(o[0], o[1], o[2], o[3]);
    op[1] = make_float4(o[4], o[5], o[6], o[7]);
    float p[8];
#pragma unroll
    for (int j = 0; j < 8; ++j) {
      float s = 0.0f;
#pragma unroll
      for (int i = 0; i < 8; ++i) s += o[i] * W23[i * 8 + j];
      p[j] = d * s;
    }
    float4* pp = (float4*)(Phat + (size_t)g * 8);
    pp[0] = make_float4(p[0], p[1], p[2], p[3]);
    pp[1] = make_float4(p[4], p[5], p[6], p[7]);
  }
}

// 8-dim u-space prop: uout = dis*( y@W + dis*acc )
__global__ void k_gp8_u(const int* __restrict__ rowptr, const int2* __restrict__ adj,
                        const float* __restrict__ uin, const float* __restrict__ y,
                        const float* __restrict__ W, const float* __restrict__ dis,
                        float* __restrict__ uout, int N) {
  int g = (blockIdx.x * blockDim.x + threadIdx.x) / GPN;
  int l = threadIdx.x & (GPN - 1);
  if (g >= N) return;
  int beg = rowptr[g], end = rowptr[g + 1];
  float a0=0,a1=0,a2=0,a3=0,a4=0,a5=0,a6=0,a7=0;
  for (int e = beg + l; e < end; e += GPN) {
    int2 sw = adj[e];
    float w = __int_as_float(sw.y);
    const float4* hp = (const float4*)(uin + (size_t)sw.x * 8);
    float4 u = hp[0], v = hp[1];
    a0 += w*u.x; a1 += w*u.y; a2 += w*u.z; a3 += w*u.w;
    a4 += w*v.x; a5 += w*v.y; a6 += w*v.z; a7 += w*v.w;
  }
#pragma unroll
  for (int off = 8; off; off >>= 1) {
    a0 += __shfl_xor(a0, off, GPN); a1 += __shfl_xor(a1, off, GPN);
    a2 += __shfl_xor(a2, off, GPN); a3 += __shfl_xor(a3, off, GPN);
    a4 += __shfl_xor(a4, off, GPN); a5 += __shfl_xor(a5, off, GPN);
    a6 += __shfl_xor(a6, off, GPN); a7 += __shfl_xor(a7, off, GPN);
  }
  if (l == 0) {
    float d = dis[g];
    const float4* yp = (const float4*)(y + (size_t)g * 8);
    float4 u = yp[0], v = yp[1];
    float yi[8] = {u.x, u.y, u.z, u.w, v.x, v.y, v.z, v.w};
    float acc[8] = {a0, a1, a2, a3, a4, a5, a6, a7};
    float o[8];
#pragma unroll
    for (int j = 0; j < 8; ++j) {
      float s = 0.0f;
#pragma unroll
      for (int i = 0; i < 8; ++i) s += yi[i] * W[i * 8 + j];
      o[j] = d * (s + d * acc[j]);
    }
    float4* op = (float4*)(uout + (size_t)g * 8);
    op[0] = make_float4(o[0], o[1], o[2], o[3]);
    op[1] = make_float4(o[4], o[5], o[6], o[7]);
  }
}

// final layer-2 prop: z = relu(y@W0 + dis*acc + b2); emit S3hat=dis*(z@W3_3), B2,B1,B0 plain
__global__ void k_gp8_fin(const int* __restrict__ rowptr, const int2* __restrict__ adj,
                          const float* __restrict__ uin, const float* __restrict__ y,
                          const float* __restrict__ W0, const float* __restrict__ b2,
                          const float* __restrict__ W3, const float* __restrict__ dis,
                          float* __restrict__ S3hat, float* __restrict__ B2,
                          float* __restrict__ B1, float* __restrict__ B0, int N) {
  int g = (blockIdx.x * blockDim.x + threadIdx.x) / GPN;
  int l = threadIdx.x & (GPN - 1);
  if (g >= N) return;
  int beg = rowptr[g], end = rowptr[g + 1];
  float a0=0,a1=0,a2=0,a3=0,a4=0,a5=0,a6=0,a7=0;
  for (int e = beg + l; e < end; e += GPN) {
    int2 sw = adj[e];
    float w = __int_as_float(sw.y);
    const float4* hp = (const float4*)(uin + (size_t)sw.x * 8);
    float4 u = hp[0], v = hp[1];
    a0 += w*u.x; a1 += w*u.y; a2 += w*u.z; a3 += w*u.w;
    a4 += w*v.x; a5 += w*v.y; a6 += w*v.z; a7 += w*v.w;
  }
#pragma unroll
  for (int off = 8; off; off >>= 1) {
    a0 += __shfl_xor(a0, off, GPN); a1 += __shfl_xor(a1, off, GPN);
    a2 += __shfl_xor(a2, off, GPN); a3 += __shfl_xor(a3, off, GPN);
    a4 += __shfl_xor(a4, off, GPN); a5 += __shfl_xor(a5, off, GPN);
    a6 += __shfl_xor(a6, off, GPN); a7 += __shfl_xor(a7, off, GPN);
  }
  if (l == 0) {
    float d = dis[g];
    const float4* yp = (const float4*)(y + (size_t)g * 8);
    float4 u = yp[0], v = yp[1];
    float yi[8] = {u.x, u.y, u.z, u.w, v.x, v.y, v.z, v.w};
    float acc[8] = {a0, a1, a2, a3, a4, a5, a6, a7};
    float z[8];
#pragma unroll
    for (int j = 0; j < 8; ++j) {
      float s = 0.0f;
#pragma unroll
      for (int i = 0; i < 8; ++i) s += yi[i] * W0[i * 8 + j];
      z[j] = relu_(s + d * acc[j] + b2[j]);
    }
    float t[4];
#pragma unroll
    for (int i = 0; i < 4; ++i) {
      float s = 0.0f;
#pragma unroll
      for (int j = 0; j < 8; ++j) s += z[j] * W3[i * 8 + j];
      t[i] = s;
    }
    B0[g] = t[0]; B1[g] = t[1]; B2[g] = t[2];
    S3hat[g] = d * t[3];
  }
}

// layer-3 mid props: uout = dis*( B + dis*acc )
__global__ void k_gp1_bu(const int* __restrict__ rowptr, const int2* __restrict__ adj,
                         const float* __restrict__ uin, const float* __restrict__ B,
                         const float* __restrict__ dis, float* __restrict__ uout, int N) {
  int g = (blockIdx.x * blockDim.x + threadIdx.x) / GPN;
  int l = threadIdx.x & (GPN - 1);
  if (g >= N) return;
  int beg = rowptr[g], end = rowptr[g + 1];
  float acc = 0.0f;
  for (int e = beg + l; e < end; e += GPN) {
    int2 sw = adj[e];
    acc += __int_as_float(sw.y) * uin[sw.x];
  }
#pragma unroll
  for (int off = 8; off; off >>= 1) acc += __shfl_xor(acc, off, GPN);
  if (l == 0) {
    float d = dis[g];
    uout[g] = d * (B[g] + d * acc);
  }
}

// final prop: r = relu(B0 + dis*acc + b3); keys; block partial sum/sumsq
__global__ void k_gp1_last(const int* __restrict__ rowptr, const int2* __restrict__ adj,
                           const float* __restrict__ uin, const float* __restrict__ B0,
                           const float* __restrict__ b3, const float* __restrict__ dis,
                           float* __restrict__ r, unsigned* __restrict__ keys,
                           double* __restrict__ partials, int N) {
  __shared__ double s1[BS];
  __shared__ double s2[BS];
  int tid = blockIdx.x * blockDim.x + threadIdx.x;
  int g = tid / GPN, l = tid & (GPN - 1);
  float rv = 0.0f;
  bool writer = false;
  if (g < N) {
    int beg = rowptr[g], end = rowptr[g + 1];
    float acc = 0.0f;
    for (int e = beg + l; e < end; e += GPN) {
      int2 sw = adj[e];
      acc += __int_as_float(sw.y) * uin[sw.x];
    }
#pragma unroll
    for (int off = 8; off; off >>= 1) acc += __shfl_xor(acc, off, GPN);
    if (l == 0) {
      float gg = B0[g] + dis[g] * acc;
      rv = relu_(gg + b3[0]);
      r[g] = rv;
      keys[g] = __float_as_uint(rv) | 0x80000000u;  // rv >= 0
      writer = true;
    }
  }
  double v = writer ? (double)rv : 0.0;
  s1[threadIdx.x] = v;
  s2[threadIdx.x] = v * v;
  __syncthreads();
  for (int off = 128; off; off >>= 1) {
    if (threadIdx.x < off) {
      s1[threadIdx.x] += s1[threadIdx.x + off];
      s2[threadIdx.x] += s2[threadIdx.x + off];
    }
    __syncthreads();
  }
  if (threadIdx.x == 0) {
    partials[2 * (size_t)blockIdx.x]     = s1[0];
    partials[2 * (size_t)blockIdx.x + 1] = s2[0];
  }
}

__global__ void k_stats(const double* __restrict__ partials, int nparts,
                        float* __restrict__ stats, int N) {
  __shared__ double s1[BS];
  __shared__ double s2[BS];
  int t = threadIdx.x;
  double a = 0.0, b = 0.0;
  for (int i = t; i < nparts; i += BS) { a += partials[2 * (size_t)i]; b += partials[2 * (size_t)i + 1]; }
  s1[t] = a; s2[t] = b;
  __syncthreads();
  for (int off = 128; off; off >>= 1) {
    if (t < off) { s1[t] += s1[t + off]; s2[t] += s2[t + off]; }
    __syncthreads();
  }
  if (t == 0) {
    double mean = s1[0] / (double)N;
    double var  = s2[0] / (double)N - mean * mean;
    stats[0] = (float)mean;
    stats[1] = (float)(1.0 / sqrt(var + 1e-5));
  }
}

// ======================= top-k radix select =======================

__global__ void k_stateinit(unsigned* __restrict__ state, const int* __restrict__ kp) {
  state[0] = 0u;
  state[1] = (unsigned)kp[0];
}

__global__ void k_hist(const unsigned* __restrict__ keys, int N,
                       const unsigned* __restrict__ state, unsigned* __restrict__ hist,
                       int shift) {
  __shared__ unsigned sh[256];
  sh[threadIdx.x] = 0;
  __syncthreads();
  unsigned prefix = state[0];
  unsigned hmask = (shift >= 24) ? 0u : (0xFFFFFFFFu << (shift + 8));
  int stride = gridDim.x * blockDim.x;
  for (int n = blockIdx.x * blockDim.x + threadIdx.x; n < N; n += stride) {
    unsigned kk = keys[n];
    if ((kk & hmask) == (prefix & hmask)) atomicAdd(&sh[(kk >> shift) & 255u], 1u);
  }
  __syncthreads();
  atomicAdd(&hist[threadIdx.x], sh[threadIdx.x]);
}

// parallel select: suffix-scan over 256 bins; also zeroes hist for next pass
__global__ void k_select(unsigned* __restrict__ state, unsigned* __restrict__ hist, int shift) {
  __shared__ unsigned sh[BS];
  int t = threadIdx.x;
  unsigned c = hist[t];
  sh[t] = c;
  __syncthreads();
  // inclusive suffix sums: sh[t] = sum_{i>=t} hist[i]
  for (int off = 1; off < BS; off <<= 1) {
    unsigned add = (t + off < BS) ? sh[t + off] : 0u; __syncthreads();
    sh[t] += add; __syncthreads();
  }
  unsigned rem = state[1];
  unsigned S = sh[t];
  if (S >= rem && (S - c) < rem) {
    state[0] |= ((unsigned)t) << shift;
    state[1] = rem - (S - c);
  }
  hist[t] = 0;
}

// normalize + mark > T; count ==T per block
__global__ void k_mark(const unsigned* __restrict__ keys, const float* __restrict__ r,
                       const float* __restrict__ stats, int N,
                       const unsigned* __restrict__ state, float* __restrict__ out,
                       unsigned* __restrict__ blkcnt) {
  unsigned T = state[0];
  float mean = stats[0], istd = stats[1];
  int n = blockIdx.x * 256 + threadIdx.x;
  int eq = 0;
  __shared__ int sh;
  if (threadIdx.x == 0) sh = 0;
  __syncthreads();
  if (n < N) {
    out[2 * (size_t)n] = (r[n] - mean) * istd;
    unsigned kk = keys[n];
    out[2 * (size_t)n + 1] = (kk > T) ? 1.0f : 0.0f;
    eq = (kk == T);
  }
  if (eq) atomicAdd(&sh, 1);
  __syncthreads();
  if (threadIdx.x == 0) blkcnt[blockIdx.x] = (unsigned)sh;
}

__global__ void k_scanP(const unsigned* __restrict__ blkcnt, unsigned* __restrict__ scanbuf, int NB) {
  __shared__ unsigned sh[BS];
  int t = threadIdx.x;
  unsigned c0 = (2 * t < NB) ? blkcnt[2 * t] : 0u;
  unsigned c1 = (2 * t + 1 < NB) ? blkcnt[2 * t + 1] : 0u;
  unsigned s = c0 + c1;
  sh[t] = s; __syncthreads();
  for (int off = 1; off < BS; off <<= 1) {
    unsigned add = (t >= off) ? sh[t - off] : 0u; __syncthreads();
    sh[t] += add; __syncthreads();
  }
  unsigned ex = sh[t] - s;
  if (2 * t < NB) scanbuf[2 * t] = ex;
  if (2 * t + 1 < NB) scanbuf[2 * t + 1] = ex + c0;
}

__global__ void k_resolve(const unsigned* __restrict__ keys, int N,
                          const unsigned* __restrict__ state,
                          const unsigned* __restrict__ scanbuf, float* __restrict__ out) {
  unsigned T = state[0];
  unsigned m = state[1];
  int n = blockIdx.x * 256 + threadIdx.x;
  if (n >= N) return;
  if (keys[n] != T) return;
  unsigned rank = scanbuf[blockIdx.x];
  int base = blockIdx.x * 256;
  for (int j = base; j < n; ++j) rank += (keys[j] == T);
  out[2 * (size_t)n + 1] = (rank < m) ? 1.0f : 0.0f;
}

// ======================= launcher =======================

extern "C" void kernel_launch(void* const* d_in, const int* in_sizes, int n_in,
                              void* d_out, int out_size, void* d_ws, size_t ws_size,
                              hipStream_t stream) {
  const float* x    = (const float*)d_in[0];
  const int*   ei   = (const int*)d_in[1];
  const float* attr = (const float*)d_in[2];
  const int*   kp   = (const int*)d_in[3];
  const float* W1   = (const float*)d_in[4];
  const float* b1   = (const float*)d_in[5];
  const float* W2   = (const float*)d_in[6];
  const float* b2   = (const float*)d_in[7];
  const float* W3   = (const float*)d_in[8];
  const float* b3   = (const float*)d_in[9];
  const int N = in_sizes[0];
  const int E = in_sizes[2];
  const int* src = ei;
  const int* dst = ei + E;
  float* out = (float*)d_out;
  const int NB    = (N + 255) / 256;
  const int NB2   = (N + 1023) / 1024;
  const int NBUCK = (N + (1 << BSH) - 1) >> BSH;
  const int chunk = (E + NBLKB - 1) / NBLKB;
  const int GGB   = (int)(((size_t)N * GPN + BS - 1) / BS);   // gather-prop blocks

  // ---- bump allocator over d_ws ----
  char* p = (char*)d_ws;
  auto alloc = [&](size_t bytes) -> char* {
    char* r = p; p += (bytes + 255) & ~(size_t)255; return r;
  };
  float*    dis    = (float*)alloc((size_t)N * 4);
  float*    xhat   = (float*)alloc((size_t)N * 4);
  float*    h1     = (float*)alloc((size_t)N * 4);
  float*    h2     = (float*)alloc((size_t)N * 4);
  float*    u1     = (float*)alloc((size_t)N * 4);
  float*    u2     = (float*)alloc((size_t)N * 4);
  float*    y      = (float*)alloc((size_t)N * 32);
  float*    Phat   = (float*)alloc((size_t)N * 32);
  float*    Qhat   = (float*)alloc((size_t)N * 32);
  float*    S3hat  = (float*)alloc((size_t)N * 4);
  float*    B2     = (float*)alloc((size_t)N * 4);
  float*    B1     = (float*)alloc((size_t)N * 4);
  float*    B0     = (float*)alloc((size_t)N * 4);
  float*    g2hat  = (float*)alloc((size_t)N * 4);
  float*    g1hat  = (float*)alloc((size_t)N * 4);
  float*    r      = (float*)alloc((size_t)N * 4);
  unsigned* keys   = (unsigned*)alloc((size_t)N * 4);
  double*   parts  = (double*)alloc((size_t)GGB * 16);
  float*    stats  = (float*)alloc(8);
  unsigned* state  = (unsigned*)alloc(8);
  unsigned* hist   = (unsigned*)alloc(1024);
  unsigned* blkcnt = (unsigned*)alloc((size_t)NB * 4);
  unsigned* scanbf = (unsigned*)alloc((size_t)NB * 4);
  int*      rowptr = (int*)alloc((size_t)(N + 1) * 4);
  int*      cursor = (int*)alloc((size_t)N * 4);
  int*      cnt    = (int*)alloc((size_t)N * 4);
  int*      bsum   = (int*)alloc(2048);
  int2*     adj    = (int2*)alloc((size_t)E * 8);
  size_t need_mid = (size_t)(p - (char*)d_ws);
  int2*     bed    = (int2*)alloc((size_t)E * 8);
  int*      bcnt   = (int*)alloc((size_t)NBUCK * NBLKB * 4);
  int*      btot   = (int*)alloc((size_t)NBUCK * 4 + 256);
  int*      bbase  = (int*)alloc((size_t)NBUCK * 4 + 256);
  size_t need_new = (size_t)(p - (char*)d_ws);

  dim3 B(BS);
  int genb = (E + BS - 1) / BS;
  dim3 GE(genb), GG(GGB), GN(NB), GB(NBUCK);

  bool use_new = (need_new <= ws_size) && (N <= 131072) && (NBUCK <= 1024);

  hipMemsetAsync(hist, 0, 1024, stream);

  if (use_new) {
    // bucketed build, no global atomics, raw weights
    k_binhist<<<dim3(NBLKB), B, 0, stream>>>(dst, bcnt, E, chunk, NBUCK);
    k_bucketscan<<<GB, B, 0, stream>>>(bcnt, btot);
    k_basescan<<<dim3(1), B, 0, stream>>>(btot, bbase, NBUCK);
    k_bin<<<dim3(NBLKB), B, 0, stream>>>(src, dst, attr, bcnt, bbase, bed, E, chunk, NBUCK);
    k_cntdeg<<<GB, B, 0, stream>>>(bed, bbase, btot, x, cnt, dis, xhat, N);
    k_scanA<<<dim3(NB2), B, 0, stream>>>(cnt, bsum, N);
    k_scanB<<<dim3(1), B, 0, stream>>>(bsum, NB2);
    k_scanC<<<dim3(NB2), B, 0, stream>>>(cnt, bsum, rowptr, (int*)nullptr, N, E);
    k_fill<<<GB, B, 0, stream>>>(bed, bbase, btot, rowptr, adj, N);
  } else {
    // fallback: global-atomic CSR build (raw weights)
    hipMemsetAsync(cnt, 0, (size_t)N * 4, stream);
    k_count<<<GE, B, 0, stream>>>(dst, cnt, E);
    k_scanA<<<dim3(NB2), B, 0, stream>>>(cnt, bsum, N);
    k_scanB<<<dim3(1), B, 0, stream>>>(bsum, NB2);
    k_scanC<<<dim3(NB2), B, 0, stream>>>(cnt, bsum, rowptr, cursor, N, E);
    k_place<<<GE, B, 0, stream>>>(src, dst, attr, cursor, adj, E);
    k_degdis<<<GG, B, 0, stream>>>(rowptr, adj, x, dis, xhat, N);
  }

  // layer 1 (u-space scalar props; y + Phat fused into last)
  k_gp1_uh<<<GG, B, 0, stream>>>(rowptr, adj, xhat, dis, h1, u1, N);
  k_gp1_uh<<<GG, B, 0, stream>>>(rowptr, adj, u1, dis, h2, u2, N);
  k_gp1_y<<<GG, B, 0, stream>>>(rowptr, adj, u2, x, h1, h2, dis, W1, b1, W2 + 3 * 64, y, Phat, N);

  // layer 2 (u-space 8-dim Horner; bases fused; layer-3 projections fused into fin)
  k_gp8_u<<<GG, B, 0, stream>>>(rowptr, adj, Phat, y, W2 + 2 * 64, dis, Qhat, N);
  k_gp8_u<<<GG, B, 0, stream>>>(rowptr, adj, Qhat, y, W2 + 1 * 64, dis, Phat, N);
  k_gp8_fin<<<GG, B, 0, stream>>>(rowptr, adj, Phat, y, W2, b2, W3, dis, S3hat, B2, B1, B0, N);

  // layer 3 (u-space scalar Horner; final prop fused with relu/keys/stats partials)
  k_gp1_bu<<<GG, B, 0, stream>>>(rowptr, adj, S3hat, B2, dis, g2hat, N);
  k_gp1_bu<<<GG, B, 0, stream>>>(rowptr, adj, g2hat, B1, dis, g1hat, N);
  k_gp1_last<<<GG, B, 0, stream>>>(rowptr, adj, g1hat, B0, b3, dis, r, keys, parts, N);

  // stats (single pass over block partials)
  k_stats<<<dim3(1), B, 0, stream>>>(parts, GGB, stats, N);

  // top-k radix select on r-keys (order invariant under affine normalize)
  k_stateinit<<<dim3(1), dim3(1), 0, stream>>>(state, kp);
  for (int shift = 24; shift >= 0; shift -= 8) {
    k_hist<<<GN, B, 0, stream>>>(keys, N, state, hist, shift);
    k_select<<<dim3(1), B, 0, stream>>>(state, hist, shift);
  }
  k_mark<<<GN, B, 0, stream>>>(keys, r, stats, N, state, out, blkcnt);
  k_scanP<<<dim3(1), B, 0, stream>>>(blkcnt, scanbf, NB);
  k_resolve<<<GN, B, 0, stream>>>(keys, N, state, scanbf, out);
}

// Round 5
// 581.860 us; speedup vs baseline: 17.6015x; 1.0575x over previous
//
#include <hip/hip_runtime.h>

#define BS 256
#define GPN 16       // lanes per node in gather props
#define NBLKB 1024   // blocks in binning pass (bucketscan VPT = NBLKB/BS = 4)
#define BSH 8        // nodes per bucket = 256
#define SMAX 400     // max buckets supported by staged k_bin (N <= 102400)

static __device__ __forceinline__ float relu_(float v) { return fmaxf(v, 0.0f); }

// ======================= bucketed CSR build (no global atomics) =======================

__global__ void k_binhist(const int* __restrict__ dst, int* __restrict__ bcnt,
                          int E, int chunk, int nbuck) {
  __shared__ int h[1024];
  int b = blockIdx.x, t = threadIdx.x;
  for (int i = t; i < nbuck; i += BS) h[i] = 0;
  __syncthreads();
  int beg = b * chunk, end = min(E, beg + chunk);
  for (int e = beg + t; e < end; e += BS) atomicAdd(&h[dst[e] >> BSH], 1);
  __syncthreads();
  for (int i = t; i < nbuck; i += BS) bcnt[(size_t)i * NBLKB + b] = h[i];
}

// per bucket: exclusive scan of its NBLKB block counts (in place); total -> btot
__global__ void k_bucketscan(int* __restrict__ bcnt, int* __restrict__ btot) {
  __shared__ int sh[BS];
  int bkt = blockIdx.x, t = threadIdx.x;
  size_t base = (size_t)bkt * NBLKB;
  int c[4], s = 0;
#pragma unroll
  for (int j = 0; j < 4; ++j) { c[j] = bcnt[base + t * 4 + j]; s += c[j]; }
  sh[t] = s; __syncthreads();
  for (int off = 1; off < BS; off <<= 1) {
    int add = (t >= off) ? sh[t - off] : 0; __syncthreads();
    sh[t] += add; __syncthreads();
  }
  int run = sh[t] - s;
#pragma unroll
  for (int j = 0; j < 4; ++j) { bcnt[base + t * 4 + j] = run; run += c[j]; }
  if (t == BS - 1) btot[bkt] = run;
}

__global__ void k_basescan(const int* __restrict__ btot, int* __restrict__ bbase, int nbuck) {
  __shared__ int sh[BS];
  int t = threadIdx.x;
  int run = 0;
  for (int c = 0; c < nbuck; c += BS) {
    int i = c + t;
    int v = (i < nbuck) ? btot[i] : 0;
    sh[t] = v; __syncthreads();
    for (int off = 1; off < BS; off <<= 1) {
      int add = (t >= off) ? sh[t - off] : 0; __syncthreads();
      sh[t] += add; __syncthreads();
    }
    if (i < nbuck) bbase[i] = run + sh[t] - v;
    run += sh[BS - 1];
    __syncthreads();
  }
}

// bin edges into bucket-contiguous bed[] = {(d_local<<17)|src, |attr|}
// LDS cursors + per-bucket 64B line staging: global writes are full-line bursts.
__global__ void k_bin(const int* __restrict__ src, const int* __restrict__ dst,
                      const float* __restrict__ attr, const int* __restrict__ bcnt,
                      const int* __restrict__ bbase, int2* __restrict__ bed,
                      int E, int chunk, int nbuck) {
  __shared__ int2 stage[SMAX][8];
  __shared__ int  fc[SMAX];
  __shared__ int  cur[SMAX];
  int b = blockIdx.x, t = threadIdx.x;
  for (int i = t; i < nbuck; i += BS) {
    cur[i] = bbase[i] + bcnt[(size_t)i * NBLKB + b];
    fc[i] = 0;
  }
  __syncthreads();
  int beg = b * chunk, end = min(E, beg + chunk);
  for (int base = beg; base < end; base += BS) {
    int e = base + t;
    if (e < end) {
      int d = dst[e];
      int bkt = d >> BSH;
      int2 rec = make_int2((int)(((unsigned)(d & ((1 << BSH) - 1)) << 17) | (unsigned)src[e]),
                           __float_as_int(fabsf(attr[e])));
      int slot = atomicAdd(&fc[bkt], 1);
      if (slot < 8) stage[bkt][slot] = rec;
      else { int gp = atomicAdd(&cur[bkt], 1); bed[gp] = rec; }  // rare spill
    }
    __syncthreads();
    for (int i = t; i < nbuck; i += BS) {
      int c = fc[i]; if (c > 8) c = 8;
      if (c == 8) {                       // flush one full 64B group
        int gp = cur[i]; cur[i] = gp + 8;
#pragma unroll
        for (int j = 0; j < 8; ++j) bed[gp + j] = stage[i][j];
        fc[i] = 0;
      }
    }
    __syncthreads();
  }
  for (int i = t; i < nbuck; i += BS) {     // drain partial groups
    int c = fc[i]; if (c > 8) c = 8;
    if (c) {
      int gp = cur[i];
      for (int j = 0; j < c; ++j) bed[gp + j] = stage[i][j];
    }
  }
}

// per bucket (256 nodes, 1 thread/node): count + degree + dis + xhat + rowptr (fused scan)
__global__ void k_cntdeg(const int2* __restrict__ bed, const int* __restrict__ bbase,
                         const int* __restrict__ btot, const float* __restrict__ x,
                         float* __restrict__ dis, float* __restrict__ xhat,
                         int* __restrict__ rowptr, int N, int E) {
  __shared__ int   lc[1 << BSH];
  __shared__ float ld[1 << BSH];
  __shared__ int   sc[1 << BSH];
  int bkt = blockIdx.x, t = threadIdx.x;
  lc[t] = 0; ld[t] = 0.f;
  __syncthreads();
  int beg = bbase[bkt], tot = btot[bkt];
  for (int i = t; i < tot; i += BS) {
    int2 rec = bed[beg + i];
    int dl = (int)((unsigned)rec.x >> 17);
    atomicAdd(&lc[dl], 1);
    atomicAdd(&ld[dl], __int_as_float(rec.y));
  }
  __syncthreads();
  int c = lc[t];
  sc[t] = c;
  __syncthreads();
  for (int off = 1; off < BS; off <<= 1) {
    int add = (t >= off) ? sc[t - off] : 0; __syncthreads();
    sc[t] += add; __syncthreads();
  }
  int n = (bkt << BSH) + t;
  if (n < N) {
    rowptr[n] = beg + sc[t] - c;
    float dg = ld[t];
    float d = (dg > 0.f) ? (1.0f / sqrtf(dg)) : 0.f;
    dis[n] = d;
    xhat[n] = d * x[n];
  }
  if (t == 0 && bkt == (int)gridDim.x - 1) rowptr[N] = E;
}

// per bucket: scatter into CSR adj with per-node 64B line staging
__global__ void k_fill(const int2* __restrict__ bed, const int* __restrict__ bbase,
                       const int* __restrict__ btot, const int* __restrict__ rowptr,
                       int2* __restrict__ adj, int N) {
  __shared__ int2 stage[1 << BSH][8];
  __shared__ int  fc[1 << BSH];
  __shared__ int  rcur[1 << BSH];
  int bkt = blockIdx.x, t = threadIdx.x;
  int n = (bkt << BSH) + t;
  rcur[t] = (n < N) ? rowptr[n] : 0;
  fc[t] = 0;
  __syncthreads();
  int beg = bbase[bkt], tot = btot[bkt];
  for (int base = 0; base < tot; base += BS) {
    int i = base + t;
    if (i < tot) {
      int2 rec = bed[beg + i];
      unsigned u = (unsigned)rec.x;
      int dl = (int)(u >> 17);
      int2 orec = make_int2((int)(u & 0x1FFFFu), rec.y);
      int slot = atomicAdd(&fc[dl], 1);
      if (slot < 8) stage[dl][slot] = orec;
      else { int gp = atomicAdd(&rcur[dl], 1); adj[gp] = orec; }
    }
    __syncthreads();
    {
      int c = fc[t]; if (c > 8) c = 8;
      if (c == 8) {
        int gp = rcur[t]; rcur[t] = gp + 8;
#pragma unroll
        for (int j = 0; j < 8; ++j) adj[gp + j] = stage[t][j];
        fc[t] = 0;
      }
    }
    __syncthreads();
  }
  {
    int c = fc[t]; if (c > 8) c = 8;
    if (c) {
      int gp = rcur[t];
      for (int j = 0; j < c; ++j) adj[gp + j] = stage[t][j];
    }
  }
}

// ======================= rowptr scan (fallback path only) =======================

__global__ void k_scanA(const int* __restrict__ cnt, int* __restrict__ bsum, int N) {
  __shared__ int sh[BS];
  int t = threadIdx.x;
  int base = blockIdx.x * 1024;
  int s = 0;
#pragma unroll
  for (int j = 0; j < 4; ++j) { int i = base + t * 4 + j; s += (i < N) ? cnt[i] : 0; }
  sh[t] = s; __syncthreads();
  for (int off = 128; off; off >>= 1) { if (t < off) sh[t] += sh[t + off]; __syncthreads(); }
  if (t == 0) bsum[blockIdx.x] = sh[0];
}

__global__ void k_scanB(int* __restrict__ bsum, int NB2) {
  __shared__ int sh[BS];
  int t = threadIdx.x;
  int v = (t < NB2) ? bsum[t] : 0;
  sh[t] = v; __syncthreads();
  for (int off = 1; off < BS; off <<= 1) {
    int add = (t >= off) ? sh[t - off] : 0; __syncthreads();
    sh[t] += add; __syncthreads();
  }
  if (t < NB2) bsum[t] = sh[t] - v;
}

__global__ void k_scanC(const int* __restrict__ cnt, const int* __restrict__ bsum,
                        int* __restrict__ rowptr, int* __restrict__ cursor, int N, int E) {
  __shared__ int sh[BS];
  int b = blockIdx.x, t = threadIdx.x;
  int base = b * 1024;
  int c[4]; int s = 0;
#pragma unroll
  for (int j = 0; j < 4; ++j) { int i = base + t * 4 + j; c[j] = (i < N) ? cnt[i] : 0; s += c[j]; }
  sh[t] = s; __syncthreads();
  for (int off = 1; off < BS; off <<= 1) {
    int add = (t >= off) ? sh[t - off] : 0; __syncthreads();
    sh[t] += add; __syncthreads();
  }
  int run = sh[t] - s + bsum[b];
#pragma unroll
  for (int j = 0; j < 4; ++j) {
    int i = base + t * 4 + j;
    if (i < N) { rowptr[i] = run; if (cursor) cursor[i] = run; run += c[j]; }
  }
  if (b == 0 && t == 0) rowptr[N] = E;
}

// ======================= fallback CSR build (global atomics) =======================

__global__ void k_count(const int* __restrict__ dst, int* __restrict__ cnt, int E) {
  int e = blockIdx.x * blockDim.x + threadIdx.x;
  if (e < E) atomicAdd(&cnt[dst[e]], 1);
}

__global__ void k_place(const int* __restrict__ src, const int* __restrict__ dst,
                        const float* __restrict__ attr, int* __restrict__ cursor,
                        int2* __restrict__ adj, int E) {
  int e = blockIdx.x * blockDim.x + threadIdx.x;
  if (e >= E) return;
  int d = dst[e];
  int pos = atomicAdd(&cursor[d], 1);
  adj[pos] = make_int2(src[e], __float_as_int(fabsf(attr[e])));
}

__global__ void k_degdis(const int* __restrict__ rowptr, const int2* __restrict__ adj,
                         const float* __restrict__ x, float* __restrict__ dis,
                         float* __restrict__ xhat, int N) {
  int g = (blockIdx.x * blockDim.x + threadIdx.x) / GPN;
  int l = threadIdx.x & (GPN - 1);
  if (g >= N) return;
  int beg = rowptr[g], end = rowptr[g + 1];
  float s = 0.0f;
  for (int e = beg + l; e < end; e += GPN) s += __int_as_float(adj[e].y);
#pragma unroll
  for (int off = 8; off; off >>= 1) s += __shfl_xor(s, off, GPN);
  if (l == 0) {
    float d = (s > 0.0f) ? (1.0f / sqrtf(s)) : 0.0f;
    dis[g] = d;
    xhat[g] = d * x[g];
  }
}

// ======================= u-space gather props =======================
// uhat = dis*h; per-edge weight stays raw |attr|; acc = sum w*uhat[src].

__global__ void k_gp1_uh(const int* __restrict__ rowptr, const int2* __restrict__ adj,
                         const float* __restrict__ uin, const float* __restrict__ dis,
                         float* __restrict__ hout, float* __restrict__ uout, int N) {
  int g = (blockIdx.x * blockDim.x + threadIdx.x) / GPN;
  int l = threadIdx.x & (GPN - 1);
  if (g >= N) return;
  int beg = rowptr[g], end = rowptr[g + 1];
  float acc = 0.0f;
  for (int e = beg + l; e < end; e += GPN) {
    int2 sw = adj[e];
    acc += __int_as_float(sw.y) * uin[sw.x];
  }
#pragma unroll
  for (int off = 8; off; off >>= 1) acc += __shfl_xor(acc, off, GPN);
  if (l == 0) {
    float d = dis[g];
    float h = d * acc;
    hout[g] = h;
    uout[g] = d * h;
  }
}

__global__ void k_gp1_y(const int* __restrict__ rowptr, const int2* __restrict__ adj,
                        const float* __restrict__ u2, const float* __restrict__ x,
                        const float* __restrict__ h1, const float* __restrict__ h2,
                        const float* __restrict__ dis, const float* __restrict__ W1,
                        const float* __restrict__ b1, const float* __restrict__ W23,
                        float* __restrict__ y, float* __restrict__ Phat, int N) {
  int g = (blockIdx.x * blockDim.x + threadIdx.x) / GPN;
  int l = threadIdx.x & (GPN - 1);
  if (g >= N) return;
  int beg = rowptr[g], end = rowptr[g + 1];
  float acc = 0.0f;
  for (int e = beg + l; e < end; e += GPN) {
    int2 sw = adj[e];
    acc += __int_as_float(sw.y) * u2[sw.x];
  }
#pragma unroll
  for (int off = 8; off; off >>= 1) acc += __shfl_xor(acc, off, GPN);
  if (l == 0) {
    float d = dis[g];
    float xv = x[g], a = h1[g], b = h2[g], c = d * acc;
    float o[8];
#pragma unroll
    for (int j = 0; j < 8; ++j)
      o[j] = relu_(xv * W1[j] + a * W1[8 + j] + b * W1[16 + j] + c * W1[24 + j] + b1[j]);
    float4* op = (float4*)(y + (size_t)g * 8);
    op[0] = make_float4(o[0], o[1], o[2], o[3]);
    op[1] = make_float4(o[4], o[5], o[6], o[7]);
    float p[8];
#pragma unroll
    for (int j = 0; j < 8; ++j) {
      float s = 0.0f;
#pragma unroll
      for (int i = 0; i < 8; ++i) s += o[i] * W23[i * 8 + j];
      p[j] = d * s;
    }
    float4* pp = (float4*)(Phat + (size_t)g * 8);
    pp[0] = make_float4(p[0], p[1], p[2], p[3]);
    pp[1] = make_float4(p[4], p[5], p[6], p[7]);
  }
}

__global__ void k_gp8_u(const int* __restrict__ rowptr, const int2* __restrict__ adj,
                        const float* __restrict__ uin, const float* __restrict__ y,
                        const float* __restrict__ W, const float* __restrict__ dis,
                        float* __restrict__ uout, int N) {
  int g = (blockIdx.x * blockDim.x + threadIdx.x) / GPN;
  int l = threadIdx.x & (GPN - 1);
  if (g >= N) return;
  int beg = rowptr[g], end = rowptr[g + 1];
  float a0=0,a1=0,a2=0,a3=0,a4=0,a5=0,a6=0,a7=0;
  for (int e = beg + l; e < end; e += GPN) {
    int2 sw = adj[e];
    float w = __int_as_float(sw.y);
    const float4* hp = (const float4*)(uin + (size_t)sw.x * 8);
    float4 u = hp[0], v = hp[1];
    a0 += w*u.x; a1 += w*u.y; a2 += w*u.z; a3 += w*u.w;
    a4 += w*v.x; a5 += w*v.y; a6 += w*v.z; a7 += w*v.w;
  }
#pragma unroll
  for (int off = 8; off; off >>= 1) {
    a0 += __shfl_xor(a0, off, GPN); a1 += __shfl_xor(a1, off, GPN);
    a2 += __shfl_xor(a2, off, GPN); a3 += __shfl_xor(a3, off, GPN);
    a4 += __shfl_xor(a4, off, GPN); a5 += __shfl_xor(a5, off, GPN);
    a6 += __shfl_xor(a6, off, GPN); a7 += __shfl_xor(a7, off, GPN);
  }
  if (l == 0) {
    float d = dis[g];
    const float4* yp = (const float4*)(y + (size_t)g * 8);
    float4 u = yp[0], v = yp[1];
    float yi[8] = {u.x, u.y, u.z, u.w, v.x, v.y, v.z, v.w};
    float acc[8] = {a0, a1, a2, a3, a4, a5, a6, a7};
    float o[8];
#pragma unroll
    for (int j = 0; j < 8; ++j) {
      float s = 0.0f;
#pragma unroll
      for (int i = 0; i < 8; ++i) s += yi[i] * W[i * 8 + j];
      o[j] = d * (s + d * acc[j]);
    }
    float4* op = (float4*)(uout + (size_t)g * 8);
    op[0] = make_float4(o[0], o[1], o[2], o[3]);
    op[1] = make_float4(o[4], o[5], o[6], o[7]);
  }
}

__global__ void k_gp8_fin(const int* __restrict__ rowptr, const int2* __restrict__ adj,
                          const float* __restrict__ uin, const float* __restrict__ y,
                          const float* __restrict__ W0, const float* __restrict__ b2,
                          const float* __restrict__ W3, const float* __restrict__ dis,
                          float* __restrict__ S3hat, float* __restrict__ B2,
                          float* __restrict__ B1, float* __restrict__ B0, int N) {
  int g = (blockIdx.x * blockDim.x + threadIdx.x) / GPN;
  int l = threadIdx.x & (GPN - 1);
  if (g >= N) return;
  int beg = rowptr[g], end = rowptr[g + 1];
  float a0=0,a1=0,a2=0,a3=0,a4=0,a5=0,a6=0,a7=0;
  for (int e = beg + l; e < end; e += GPN) {
    int2 sw = adj[e];
    float w = __int_as_float(sw.y);
    const float4* hp = (const float4*)(uin + (size_t)sw.x * 8);
    float4 u = hp[0], v = hp[1];
    a0 += w*u.x; a1 += w*u.y; a2 += w*u.z; a3 += w*u.w;
    a4 += w*v.x; a5 += w*v.y; a6 += w*v.z; a7 += w*v.w;
  }
#pragma unroll
  for (int off = 8; off; off >>= 1) {
    a0 += __shfl_xor(a0, off, GPN); a1 += __shfl_xor(a1, off, GPN);
    a2 += __shfl_xor(a2, off, GPN); a3 += __shfl_xor(a3, off, GPN);
    a4 += __shfl_xor(a4, off, GPN); a5 += __shfl_xor(a5, off, GPN);
    a6 += __shfl_xor(a6, off, GPN); a7 += __shfl_xor(a7, off, GPN);
  }
  if (l == 0) {
    float d = dis[g];
    const float4* yp = (const float4*)(y + (size_t)g * 8);
    float4 u = yp[0], v = yp[1];
    float yi[8] = {u.x, u.y, u.z, u.w, v.x, v.y, v.z, v.w};
    float acc[8] = {a0, a1, a2, a3, a4, a5, a6, a7};
    float z[8];
#pragma unroll
    for (int j = 0; j < 8; ++j) {
      float s = 0.0f;
#pragma unroll
      for (int i = 0; i < 8; ++i) s += yi[i] * W0[i * 8 + j];
      z[j] = relu_(s + d * acc[j] + b2[j]);
    }
    float t[4];
#pragma unroll
    for (int i = 0; i < 4; ++i) {
      float s = 0.0f;
#pragma unroll
      for (int j = 0; j < 8; ++j) s += z[j] * W3[i * 8 + j];
      t[i] = s;
    }
    B0[g] = t[0]; B1[g] = t[1]; B2[g] = t[2];
    S3hat[g] = d * t[3];
  }
}

__global__ void k_gp1_bu(const int* __restrict__ rowptr, const int2* __restrict__ adj,
                         const float* __restrict__ uin, const float* __restrict__ B,
                         const float* __restrict__ dis, float* __restrict__ uout, int N) {
  int g = (blockIdx.x * blockDim.x + threadIdx.x) / GPN;
  int l = threadIdx.x & (GPN - 1);
  if (g >= N) return;
  int beg = rowptr[g], end = rowptr[g + 1];
  float acc = 0.0f;
  for (int e = beg + l; e < end; e += GPN) {
    int2 sw = adj[e];
    acc += __int_as_float(sw.y) * uin[sw.x];
  }
#pragma unroll
  for (int off = 8; off; off >>= 1) acc += __shfl_xor(acc, off, GPN);
  if (l == 0) {
    float d = dis[g];
    uout[g] = d * (B[g] + d * acc);
  }
}

__global__ void k_gp1_last(const int* __restrict__ rowptr, const int2* __restrict__ adj,
                           const float* __restrict__ uin, const float* __restrict__ B0,
                           const float* __restrict__ b3, const float* __restrict__ dis,
                           float* __restrict__ r, unsigned* __restrict__ keys,
                           double* __restrict__ partials, int N) {
  __shared__ double s1[BS];
  __shared__ double s2[BS];
  int tid = blockIdx.x * blockDim.x + threadIdx.x;
  int g = tid / GPN, l = tid & (GPN - 1);
  float rv = 0.0f;
  bool writer = false;
  if (g < N) {
    int beg = rowptr[g], end = rowptr[g + 1];
    float acc = 0.0f;
    for (int e = beg + l; e < end; e += GPN) {
      int2 sw = adj[e];
      acc += __int_as_float(sw.y) * uin[sw.x];
    }
#pragma unroll
    for (int off = 8; off; off >>= 1) acc += __shfl_xor(acc, off, GPN);
    if (l == 0) {
      float gg = B0[g] + dis[g] * acc;
      rv = relu_(gg + b3[0]);
      r[g] = rv;
      keys[g] = __float_as_uint(rv) | 0x80000000u;  // rv >= 0
      writer = true;
    }
  }
  double v = writer ? (double)rv : 0.0;
  s1[threadIdx.x] = v;
  s2[threadIdx.x] = v * v;
  __syncthreads();
  for (int off = 128; off; off >>= 1) {
    if (threadIdx.x < off) {
      s1[threadIdx.x] += s1[threadIdx.x + off];
      s2[threadIdx.x] += s2[threadIdx.x + off];
    }
    __syncthreads();
  }
  if (threadIdx.x == 0) {
    partials[2 * (size_t)blockIdx.x]     = s1[0];
    partials[2 * (size_t)blockIdx.x + 1] = s2[0];
  }
}

__global__ void k_stats(const double* __restrict__ partials, int nparts,
                        float* __restrict__ stats, int N) {
  __shared__ double s1[BS];
  __shared__ double s2[BS];
  int t = threadIdx.x;
  double a = 0.0, b = 0.0;
  for (int i = t; i < nparts; i += BS) { a += partials[2 * (size_t)i]; b += partials[2 * (size_t)i + 1]; }
  s1[t] = a; s2[t] = b;
  __syncthreads();
  for (int off = 128; off; off >>= 1) {
    if (t < off) { s1[t] += s1[t + off]; s2[t] += s2[t + off]; }
    __syncthreads();
  }
  if (t == 0) {
    double mean = s1[0] / (double)N;
    double var  = s2[0] / (double)N - mean * mean;
    stats[0] = (float)mean;
    stats[1] = (float)(1.0 / sqrt(var + 1e-5));
  }
}

// ======================= top-k radix select =======================

__global__ void k_stateinit(unsigned* __restrict__ state, const int* __restrict__ kp) {
  state[0] = 0u;
  state[1] = (unsigned)kp[0];
}

__global__ void k_hist(const unsigned* __restrict__ keys, int N,
                       const unsigned* __restrict__ state, unsigned* __restrict__ hist,
                       int shift) {
  __shared__ unsigned sh[256];
  sh[threadIdx.x] = 0;
  __syncthreads();
  unsigned prefix = state[0];
  unsigned hmask = (shift >= 24) ? 0u : (0xFFFFFFFFu << (shift + 8));
  int stride = gridDim.x * blockDim.x;
  for (int n = blockIdx.x * blockDim.x + threadIdx.x; n < N; n += stride) {
    unsigned kk = keys[n];
    if ((kk & hmask) == (prefix & hmask)) atomicAdd(&sh[(kk >> shift) & 255u], 1u);
  }
  __syncthreads();
  atomicAdd(&hist[threadIdx.x], sh[threadIdx.x]);
}

__global__ void k_select(unsigned* __restrict__ state, unsigned* __restrict__ hist, int shift) {
  __shared__ unsigned sh[BS];
  int t = threadIdx.x;
  unsigned c = hist[t];
  sh[t] = c;
  __syncthreads();
  for (int off = 1; off < BS; off <<= 1) {
    unsigned add = (t + off < BS) ? sh[t + off] : 0u; __syncthreads();
    sh[t] += add; __syncthreads();
  }
  unsigned rem = state[1];
  unsigned S = sh[t];
  if (S >= rem && (S - c) < rem) {
    state[0] |= ((unsigned)t) << shift;
    state[1] = rem - (S - c);
  }
  hist[t] = 0;
}

__global__ void k_mark(const unsigned* __restrict__ keys, const float* __restrict__ r,
                       const float* __restrict__ stats, int N,
                       const unsigned* __restrict__ state, float* __restrict__ out,
                       unsigned* __restrict__ blkcnt) {
  unsigned T = state[0];
  float mean = stats[0], istd = stats[1];
  int n = blockIdx.x * 256 + threadIdx.x;
  int eq = 0;
  __shared__ int sh;
  if (threadIdx.x == 0) sh = 0;
  __syncthreads();
  if (n < N) {
    out[2 * (size_t)n] = (r[n] - mean) * istd;
    unsigned kk = keys[n];
    out[2 * (size_t)n + 1] = (kk > T) ? 1.0f : 0.0f;
    eq = (kk == T);
  }
  if (eq) atomicAdd(&sh, 1);
  __syncthreads();
  if (threadIdx.x == 0) blkcnt[blockIdx.x] = (unsigned)sh;
}

__global__ void k_scanP(const unsigned* __restrict__ blkcnt, unsigned* __restrict__ scanbuf, int NB) {
  __shared__ unsigned sh[BS];
  int t = threadIdx.x;
  unsigned c0 = (2 * t < NB) ? blkcnt[2 * t] : 0u;
  unsigned c1 = (2 * t + 1 < NB) ? blkcnt[2 * t + 1] : 0u;
  unsigned s = c0 + c1;
  sh[t] = s; __syncthreads();
  for (int off = 1; off < BS; off <<= 1) {
    unsigned add = (t >= off) ? sh[t - off] : 0u; __syncthreads();
    sh[t] += add; __syncthreads();
  }
  unsigned ex = sh[t] - s;
  if (2 * t < NB) scanbuf[2 * t] = ex;
  if (2 * t + 1 < NB) scanbuf[2 * t + 1] = ex + c0;
}

__global__ void k_resolve(const unsigned* __restrict__ keys, int N,
                          const unsigned* __restrict__ state,
                          const unsigned* __restrict__ scanbuf, float* __restrict__ out) {
  unsigned T = state[0];
  unsigned m = state[1];
  int n = blockIdx.x * 256 + threadIdx.x;
  if (n >= N) return;
  if (keys[n] != T) return;
  unsigned rank = scanbuf[blockIdx.x];
  int base = blockIdx.x * 256;
  for (int j = base; j < n; ++j) rank += (keys[j] == T);
  out[2 * (size_t)n + 1] = (rank < m) ? 1.0f : 0.0f;
}

// ======================= launcher =======================

extern "C" void kernel_launch(void* const* d_in, const int* in_sizes, int n_in,
                              void* d_out, int out_size, void* d_ws, size_t ws_size,
                              hipStream_t stream) {
  const float* x    = (const float*)d_in[0];
  const int*   ei   = (const int*)d_in[1];
  const float* attr = (const float*)d_in[2];
  const int*   kp   = (const int*)d_in[3];
  const float* W1   = (const float*)d_in[4];
  const float* b1   = (const float*)d_in[5];
  const float* W2   = (const float*)d_in[6];
  const float* b2   = (const float*)d_in[7];
  const float* W3   = (const float*)d_in[8];
  const float* b3   = (const float*)d_in[9];
  const int N = in_sizes[0];
  const int E = in_sizes[2];
  const int* src = ei;
  const int* dst = ei + E;
  float* out = (float*)d_out;
  const int NB    = (N + 255) / 256;
  const int NB2   = (N + 1023) / 1024;
  const int NBUCK = (N + (1 << BSH) - 1) >> BSH;
  const int chunk = (E + NBLKB - 1) / NBLKB;
  const int GGB   = (int)(((size_t)N * GPN + BS - 1) / BS);   // gather-prop blocks

  // ---- bump allocator over d_ws ----
  char* p = (char*)d_ws;
  auto alloc = [&](size_t bytes) -> char* {
    char* r = p; p += (bytes + 255) & ~(size_t)255; return r;
  };
  float*    dis    = (float*)alloc((size_t)N * 4);
  float*    xhat   = (float*)alloc((size_t)N * 4);
  float*    h1     = (float*)alloc((size_t)N * 4);
  float*    h2     = (float*)alloc((size_t)N * 4);
  float*    u1     = (float*)alloc((size_t)N * 4);
  float*    u2     = (float*)alloc((size_t)N * 4);
  float*    y      = (float*)alloc((size_t)N * 32);
  float*    Phat   = (float*)alloc((size_t)N * 32);
  float*    Qhat   = (float*)alloc((size_t)N * 32);
  float*    S3hat  = (float*)alloc((size_t)N * 4);
  float*    B2     = (float*)alloc((size_t)N * 4);
  float*    B1     = (float*)alloc((size_t)N * 4);
  float*    B0     = (float*)alloc((size_t)N * 4);
  float*    g2hat  = (float*)alloc((size_t)N * 4);
  float*    g1hat  = (float*)alloc((size_t)N * 4);
  float*    r      = (float*)alloc((size_t)N * 4);
  unsigned* keys   = (unsigned*)alloc((size_t)N * 4);
  double*   parts  = (double*)alloc((size_t)GGB * 16);
  float*    stats  = (float*)alloc(8);
  unsigned* state  = (unsigned*)alloc(8);
  unsigned* hist   = (unsigned*)alloc(1024);
  unsigned* blkcnt = (unsigned*)alloc((size_t)NB * 4);
  unsigned* scanbf = (unsigned*)alloc((size_t)NB * 4);
  int*      rowptr = (int*)alloc((size_t)(N + 1) * 4);
  int*      cursor = (int*)alloc((size_t)N * 4);
  int*      cnt    = (int*)alloc((size_t)N * 4);
  int*      bsum   = (int*)alloc(2048);
  int2*     adj    = (int2*)alloc((size_t)E * 8);
  size_t need_mid = (size_t)(p - (char*)d_ws);
  int2*     bed    = (int2*)alloc((size_t)E * 8);
  int*      bcnt   = (int*)alloc((size_t)NBUCK * NBLKB * 4);
  int*      btot   = (int*)alloc((size_t)NBUCK * 4 + 256);
  int*      bbase  = (int*)alloc((size_t)NBUCK * 4 + 256);
  size_t need_new = (size_t)(p - (char*)d_ws);

  dim3 B(BS);
  int genb = (E + BS - 1) / BS;
  dim3 GE(genb), GG(GGB), GN(NB), GB(NBUCK);

  bool use_new = (need_new <= ws_size) && (N <= 131072) && (NBUCK <= SMAX);

  hipMemsetAsync(hist, 0, 1024, stream);

  if (use_new) {
    // bucketed build: no global atomics, staged 64B line writes
    k_binhist<<<dim3(NBLKB), B, 0, stream>>>(dst, bcnt, E, chunk, NBUCK);
    k_bucketscan<<<GB, B, 0, stream>>>(bcnt, btot);
    k_basescan<<<dim3(1), B, 0, stream>>>(btot, bbase, NBUCK);
    k_bin<<<dim3(NBLKB), B, 0, stream>>>(src, dst, attr, bcnt, bbase, bed, E, chunk, NBUCK);
    k_cntdeg<<<GB, B, 0, stream>>>(bed, bbase, btot, x, dis, xhat, rowptr, N, E);
    k_fill<<<GB, B, 0, stream>>>(bed, bbase, btot, rowptr, adj, N);
  } else {
    // fallback: global-atomic CSR build (raw weights)
    hipMemsetAsync(cnt, 0, (size_t)N * 4, stream);
    k_count<<<GE, B, 0, stream>>>(dst, cnt, E);
    k_scanA<<<dim3(NB2), B, 0, stream>>>(cnt, bsum, N);
    k_scanB<<<dim3(1), B, 0, stream>>>(bsum, NB2);
    k_scanC<<<dim3(NB2), B, 0, stream>>>(cnt, bsum, rowptr, cursor, N, E);
    k_place<<<GE, B, 0, stream>>>(src, dst, attr, cursor, adj, E);
    k_degdis<<<GG, B, 0, stream>>>(rowptr, adj, x, dis, xhat, N);
  }

  // layer 1 (u-space scalar props; y + Phat fused into last)
  k_gp1_uh<<<GG, B, 0, stream>>>(rowptr, adj, xhat, dis, h1, u1, N);
  k_gp1_uh<<<GG, B, 0, stream>>>(rowptr, adj, u1, dis, h2, u2, N);
  k_gp1_y<<<GG, B, 0, stream>>>(rowptr, adj, u2, x, h1, h2, dis, W1, b1, W2 + 3 * 64, y, Phat, N);

  // layer 2 (u-space 8-dim Horner; bases fused; layer-3 projections fused into fin)
  k_gp8_u<<<GG, B, 0, stream>>>(rowptr, adj, Phat, y, W2 + 2 * 64, dis, Qhat, N);
  k_gp8_u<<<GG, B, 0, stream>>>(rowptr, adj, Qhat, y, W2 + 1 * 64, dis, Phat, N);
  k_gp8_fin<<<GG, B, 0, stream>>>(rowptr, adj, Phat, y, W2, b2, W3, dis, S3hat, B2, B1, B0, N);

  // layer 3 (u-space scalar Horner; final prop fused with relu/keys/stats partials)
  k_gp1_bu<<<GG, B, 0, stream>>>(rowptr, adj, S3hat, B2, dis, g2hat, N);
  k_gp1_bu<<<GG, B, 0, stream>>>(rowptr, adj, g2hat, B1, dis, g1hat, N);
  k_gp1_last<<<GG, B, 0, stream>>>(rowptr, adj, g1hat, B0, b3, dis, r, keys, parts, N);

  // stats (single pass over block partials)
  k_stats<<<dim3(1), B, 0, stream>>>(parts, GGB, stats, N);

  // top-k radix select on r-keys (order invariant under affine normalize)
  k_stateinit<<<dim3(1), dim3(1), 0, stream>>>(state, kp);
  for (int shift = 24; shift >= 0; shift -= 8) {
    k_hist<<<GN, B, 0, stream>>>(keys, N, state, hist, shift);
    k_select<<<dim3(1), B, 0, stream>>>(state, hist, shift);
  }
  k_mark<<<GN, B, 0, stream>>>(keys, r, stats, N, state, out, blkcnt);
  k_scanP<<<dim3(1), B, 0, stream>>>(blkcnt, scanbf, NB);
  k_resolve<<<GN, B, 0, stream>>>(keys, N, state, scanbf, out);
}